// Round 2
// baseline (1654.186 us; speedup 1.0000x reference)
//
#include <hip/hip_runtime.h>
#include <stdint.h>

#define AS1 __attribute__((address_space(1)))
#define AS3 __attribute__((address_space(3)))

typedef __bf16 bf16x8 __attribute__((ext_vector_type(8)));
typedef float  f32x4  __attribute__((ext_vector_type(4)));

__device__ __forceinline__ void gl_lds16(const void* g, void* l) {
    __builtin_amdgcn_global_load_lds((AS1 void*)g, (AS3 void*)l, 16, 0, 0);
}

// f32 -> bf16 round-to-nearest-even
__device__ __forceinline__ ushort f2bf(float f) {
    unsigned x = __float_as_uint(f);
    return (ushort)((x + 0x7fffu + ((x >> 16) & 1u)) >> 16);
}

__device__ __forceinline__ void atomAddF(float* p, float v) {
    unsafeAtomicAdd(p, v);  // HW global_atomic_add_f32 on gfx950
}

// ---------------------------------------------------------------------------
// GEMM: C[m][n] = sum_k A[m][k] * BT[n][k]   (128x128 tile, BK=32, bf16 MFMA)
// AMODE 0: A flat [m][K]; blockIdx.z = batch (A,B offset by z*M*K / z*N*K)
// AMODE 1: conv gather, m=(b*49+p), k=(s*Cin+ci); blockIdx.z = split-K chunk
//          (ci range [z*Cin/splitZ, (z+1)*Cin/splitZ))
// EPI 0: atomicAdd into OF[(b*512+n)*49+p]  (conv_reduce / conv_out partials)
// EPI 1: conv_kv  -> n<512: OU0 = kbuf [p][j][512]; else OU1 = vbuf [p][j][512]
// EPI 2: scores   -> OF[z*256+m][n]  (256 wide)
// EPI 3: PV       -> OF[z*256+m][n]  (512 wide)
// ---------------------------------------------------------------------------
template <int AMODE, int EPI>
__global__ __launch_bounds__(256, 4) void gemm_bt(
    const ushort* __restrict__ A, const ushort* __restrict__ BT,
    float* __restrict__ OF, ushort* __restrict__ OU0, ushort* __restrict__ OU1,
    int M, int N, int K, int Cin, int Ksegs, int splitZ) {
    __shared__ ushort As[128 * 32];
    __shared__ ushort Bs[128 * 32];

    const int t = threadIdx.x;
    const int lane = t & 63;
    const int wave = t >> 6;
    const int wm = wave & 1, wn = wave >> 1;
    const int blockN = blockIdx.x * 128;
    const int blockM = blockIdx.y * 128;
    const int z = blockIdx.z;

    const char* Ab = (const char*)A;
    const char* Bb = (const char*)BT;
    if (AMODE == 0) {
        Ab += (size_t)z * (size_t)M * (size_t)K * 2;
        Bb += (size_t)z * (size_t)N * (size_t)K * 2;
    }

    const int rS = t >> 2;              // staging row 0..63 (and +64)
    const int seg = (t & 3) * 16;       // 16B segment within a 64B K-tile row

    unsigned abase0, abase1;
    if (AMODE == 1) {
        int m0 = blockM + rS, m1 = m0 + 64;
        int b0 = m0 / 49, p0 = m0 % 49;
        int b1 = m1 / 49, p1 = m1 % 49;
        abase0 = (unsigned)(((b0 * 9 + p0 / 7) * 9 + p0 % 7) * Cin);
        abase1 = (unsigned)(((b1 * 9 + p1 / 7) * 9 + p1 % 7) * Cin);
    } else {
        abase0 = (unsigned)((blockM + rS) * K);
        abase1 = abase0 + (unsigned)(64 * K);
    }
    const unsigned bbase0 = (unsigned)((blockN + rS) * K);
    const unsigned bbase1 = bbase0 + (unsigned)(64 * K);

    f32x4 zero = {0.f, 0.f, 0.f, 0.f};
    f32x4 acc[4][4];
    for (int i = 0; i < 4; i++)
        for (int j = 0; j < 4; j++) acc[i][j] = zero;

    const unsigned chunk = (AMODE == 1) ? (unsigned)(Cin / splitZ) : (unsigned)K;
    const unsigned ciBase = (AMODE == 1) ? (unsigned)z * chunk : 0u;
    const int citers = (int)(chunk / 32);
    const int nseg = (AMODE == 1) ? Ksegs : 1;

    for (int s = 0; s < nseg; ++s) {
        const char *aseg0, *aseg1, *bseg0, *bseg1;
        if (AMODE == 1) {
            unsigned shift = (unsigned)(((s / 3) * 9 + (s % 3)) * Cin) + ciBase;
            aseg0 = Ab + (size_t)(abase0 + shift) * 2 + seg;
            aseg1 = Ab + (size_t)(abase1 + shift) * 2 + seg;
            unsigned bshift = (unsigned)(s * Cin) + ciBase;
            bseg0 = Bb + (size_t)(bbase0 + bshift) * 2 + seg;
            bseg1 = Bb + (size_t)(bbase1 + bshift) * 2 + seg;
        } else {
            aseg0 = Ab + (size_t)abase0 * 2 + seg;
            aseg1 = Ab + (size_t)abase1 * 2 + seg;
            bseg0 = Bb + (size_t)bbase0 * 2 + seg;
            bseg1 = Bb + (size_t)bbase1 * 2 + seg;
        }

        for (int ct = 0; ct < citers; ++ct) {
            __syncthreads();  // previous compute done reading LDS
            gl_lds16(aseg0 + ct * 64, (char*)As + t * 16);
            gl_lds16(aseg1 + ct * 64, (char*)As + 4096 + t * 16);
            gl_lds16(bseg0 + ct * 64, (char*)Bs + t * 16);
            gl_lds16(bseg1 + ct * 64, (char*)Bs + 4096 + t * 16);
            __syncthreads();  // staging visible

            const ushort* Ap = As + (wm * 64 + (lane & 15)) * 32 + (lane >> 4) * 8;
            const ushort* Bp = Bs + (wn * 64 + (lane & 15)) * 32 + (lane >> 4) * 8;
            bf16x8 af[4], bfr[4];
#pragma unroll
            for (int i = 0; i < 4; i++) {
                af[i] = *(const bf16x8*)(Ap + i * 16 * 32);
                bfr[i] = *(const bf16x8*)(Bp + i * 16 * 32);
            }
#pragma unroll
            for (int i = 0; i < 4; i++)
#pragma unroll
                for (int j = 0; j < 4; j++)
                    acc[i][j] = __builtin_amdgcn_mfma_f32_16x16x32_bf16(af[i], bfr[j], acc[i][j], 0, 0, 0);
        }
    }

    // epilogue: C/D layout col=lane&15, row=(lane>>4)*4+r  [m89/m91 verified]
    const int mrow = (lane >> 4) * 4;
    const int ncol = lane & 15;
#pragma unroll
    for (int i = 0; i < 4; i++) {
#pragma unroll
        for (int j = 0; j < 4; j++) {
            f32x4 v = acc[i][j];
#pragma unroll
            for (int r = 0; r < 4; r++) {
                int m = blockM + wm * 64 + i * 16 + mrow + r;
                int n = blockN + wn * 64 + j * 16 + ncol;
                float val = v[r];
                if (EPI == 0) {
                    int b = m / 49, p = m % 49;
                    atomAddF(&OF[(size_t)(b * 512 + n) * 49 + p], val);
                } else if (EPI == 1) {
                    int j2 = m / 49, p = m % 49;
                    if (n < 512)
                        OU0[(size_t)(p * 256 + j2) * 512 + n] = f2bf(val);
                    else
                        OU1[(size_t)(p * 256 + j2) * 512 + (n - 512)] = f2bf(val);
                } else if (EPI == 2) {
                    OF[((size_t)z * 256 + m) * 256 + n] = val;
                } else {
                    OF[((size_t)z * 256 + m) * 512 + n] = val;
                }
            }
        }
    }
}

// zero a range (uint4 grid-stride)
__global__ void zero_k(uint4* __restrict__ p, int n4) {
    uint4 zz = {0, 0, 0, 0};
    for (int i = blockIdx.x * blockDim.x + threadIdx.x; i < n4; i += gridDim.x * blockDim.x) p[i] = zz;
}

// uint4 grid-stride d2d copy
__global__ void copy_k(const uint4* __restrict__ s, uint4* __restrict__ d, int n4) {
    for (int i = blockIdx.x * blockDim.x + threadIdx.x; i < n4; i += gridDim.x * blockDim.x) d[i] = s[i];
}

// zero only the 32 border cells of a padded [256][9][9][C] bf16 tensor
__global__ void border_k(ushort* __restrict__ base, int C, int nvec) {
    int id = blockIdx.x * 256 + threadIdx.x;
    if (id >= nvec) return;
    int cpc = C >> 2;
    int c4 = (id % cpc) * 4;
    int r = id / cpc;
    int cell = r & 31, b = r >> 5;
    int hp, wp;
    if (cell < 9) { hp = 0; wp = cell; }
    else if (cell < 18) { hp = 8; wp = cell - 9; }
    else { int e2 = cell - 18; hp = 1 + (e2 >> 1); wp = (e2 & 1) ? 8 : 0; }
    ushort4 zz = {0, 0, 0, 0};
    *(ushort4*)(base + ((size_t)(b * 9 + hp) * 9 + wp) * C + c4) = zz;
}

// bbox_featx f32 [b][2304][49] -> x0T bf16 [b][9][9][2304] interior
// block = (ci-tile of 576, b); coalesced read -> LDS -> coalesced write
__global__ __launch_bounds__(256) void cast_x0_k(const float* __restrict__ in, ushort* __restrict__ out) {
    __shared__ ushort tl[576 * 49];  // [ci][p] within tile, 56448 B
    int cit = blockIdx.x, b = blockIdx.y, t = threadIdx.x;
    const float* src = in + ((size_t)b * 2304 + cit * 576) * 49;
    for (int e4 = t; e4 < 7056; e4 += 256) {  // 7056 float4 = 576*49 f32
        float4 v = *(const float4*)(src + e4 * 4);
        ushort4 u;
        u.x = f2bf(v.x); u.y = f2bf(v.y); u.z = f2bf(v.z); u.w = f2bf(v.w);
        *(ushort4*)(tl + e4 * 4) = u;
    }
    __syncthreads();
    for (int e4 = t; e4 < 7056; e4 += 256) {  // 49 p * 144 c4-groups
        int p = e4 / 144, c4 = (e4 % 144) * 4;
        ushort4 u;
        u.x = tl[c4 * 49 + p]; u.y = tl[(c4 + 1) * 49 + p];
        u.z = tl[(c4 + 2) * 49 + p]; u.w = tl[(c4 + 3) * 49 + p];
        *(ushort4*)(out + (size_t)((b * 9 + p / 7 + 1) * 9 + p % 7 + 1) * 2304 + cit * 576 + c4) = u;
    }
}

// x f32 [b][512][49] -> xpad bf16 [b][9][9][512] interior (LDS transpose)
__global__ __launch_bounds__(256) void xpad_k(const float* __restrict__ x, ushort* __restrict__ xp) {
    __shared__ float lf[256 * 49];  // [c][p] half-channel tile, 50176 B
    int h = blockIdx.x, b = blockIdx.y, t = threadIdx.x;
    const float* src = x + (size_t)b * 25088 + h * 12544;
    for (int e4 = t; e4 < 3136; e4 += 256)
        *(float4*)(lf + e4 * 4) = *(const float4*)(src + e4 * 4);
    __syncthreads();
    for (int e4 = t; e4 < 3136; e4 += 256) {  // 49 p * 64 c4-groups
        int p = e4 >> 6, c4 = (e4 & 63) * 4;
        ushort4 u;
        u.x = f2bf(lf[c4 * 49 + p]); u.y = f2bf(lf[(c4 + 1) * 49 + p]);
        u.z = f2bf(lf[(c4 + 2) * 49 + p]); u.w = f2bf(lf[(c4 + 3) * 49 + p]);
        *(ushort4*)(xp + (size_t)((b * 9 + p / 7 + 1) * 9 + p % 7 + 1) * 512 + h * 256 + c4) = u;
    }
}

// weight f32 [co][Cin][9] -> bf16 [co][9][Cin]  (one block per co)
__global__ void cast_w_k(const float* __restrict__ in, ushort* __restrict__ out, int Cin) {
    __shared__ float lds[256 * 9];
    int co = blockIdx.x, t = threadIdx.x;
    for (int ci0 = 0; ci0 < Cin; ci0 += 256) {
        const float* src = in + ((size_t)co * Cin + ci0 + t) * 9;
#pragma unroll
        for (int j = 0; j < 9; j++) lds[t * 9 + j] = src[j];
        __syncthreads();
#pragma unroll
        for (int s = 0; s < 9; s++) out[((size_t)co * 9 + s) * Cin + ci0 + t] = f2bf(lds[t * 9 + s]);
        __syncthreads();
    }
}

// windowed sums of w_q per spatial pos: WSQ[p][ci][co]
__global__ void wsq_k(const float* __restrict__ wq, float* __restrict__ WSQ) {
    int p = blockIdx.x, co = threadIdx.x;
    int h = p / 7, w = p % 7;
#pragma unroll
    for (int ci = 0; ci < 2; ci++) {
        float a = 0.f;
        for (int kh = 0; kh < 3; kh++) {
            int hi = h + kh - 1;
            if (hi < 0 || hi > 6) continue;
            for (int kw = 0; kw < 3; kw++) {
                int wi = w + kw - 1;
                if (wi < 0 || wi > 6) continue;
                a += wq[(((size_t)co * 2 + ci) * 3 + kh) * 3 + kw];
            }
        }
        WSQ[((size_t)p * 2 + ci) * 512 + co] = a;
    }
}

// q bf16 [p][b][512], scaled by 1/sqrt(512)
__global__ void qgen_k(const float* __restrict__ status, const float* __restrict__ rois,
                       const float* __restrict__ WSQ, ushort* __restrict__ qb) {
    int b = blockIdx.x, p = blockIdx.y, t = threadIdx.x;
    float st0 = status[b * 2], st1 = rois[b * 2 + 1];
    int c = t * 2;
    const float* w0 = WSQ + (size_t)p * 2 * 512;
    const float sc = 0.04419417382415922f;  // 1/sqrt(512)
    float q0 = (st0 * w0[c] + st1 * w0[512 + c]) * sc;
    float q1 = (st0 * w0[c + 1] + st1 * w0[512 + c + 1]) * sc;
    unsigned u = (unsigned)f2bf(q0) | ((unsigned)f2bf(q1) << 16);
    *(unsigned*)(qb + ((size_t)p * 256 + b) * 512 + c) = u;
}

// softmax over rows of 256 (S f32 -> att bf16), one wave per row
__global__ void softmax_k(const float* __restrict__ S, ushort* __restrict__ att) {
    int row = blockIdx.x * 4 + (threadIdx.x >> 6);
    int lane = threadIdx.x & 63;
    const float4 sv = *(const float4*)(S + (size_t)row * 256 + lane * 4);
    float m = fmaxf(fmaxf(sv.x, sv.y), fmaxf(sv.z, sv.w));
    for (int o = 32; o > 0; o >>= 1) m = fmaxf(m, __shfl_xor(m, o));
    float e0 = __expf(sv.x - m), e1 = __expf(sv.y - m);
    float e2 = __expf(sv.z - m), e3 = __expf(sv.w - m);
    float s = e0 + e1 + e2 + e3;
    for (int o = 32; o > 0; o >>= 1) s += __shfl_xor(s, o);
    float inv = 1.f / s;
    ushort4 o4;
    o4.x = f2bf(e0 * inv); o4.y = f2bf(e1 * inv);
    o4.z = f2bf(e2 * inv); o4.w = f2bf(e3 * inv);
    *(ushort4*)(att + (size_t)row * 256 + lane * 4) = o4;
}

// vbuf [p][j][512] -> vbufT [p][512][j] (64x64 LDS tiles)
__global__ void transpose_v_k(const ushort* __restrict__ vb, ushort* __restrict__ vt) {
    __shared__ ushort tl[64][66];
    int p = blockIdx.z, j0 = blockIdx.y * 64, c0 = blockIdx.x * 64;
    int t = threadIdx.x;
#pragma unroll
    for (int i = 0; i < 4; i++) {
        int e = i * 1024 + t * 4;
        int j = e >> 6, c = e & 63;
        ushort4 v = *(const ushort4*)(vb + ((size_t)p * 256 + j0 + j) * 512 + c0 + c);
        tl[j][c] = v.x; tl[j][c + 1] = v.y; tl[j][c + 2] = v.z; tl[j][c + 3] = v.w;
    }
    __syncthreads();
#pragma unroll
    for (int i = 0; i < 4; i++) {
        int e = i * 1024 + t * 4;
        int cc = e >> 6, jj = e & 63;
        ushort4 o;
        o.x = tl[jj][cc]; o.y = tl[jj + 1][cc]; o.z = tl[jj + 2][cc]; o.w = tl[jj + 3][cc];
        *(ushort4*)(vt + ((size_t)p * 512 + c0 + cc) * 256 + j0 + jj) = o;
    }
}

// layernorm over (c,p) per b + gamma/beta + relu -> vpad bf16 [b][9][9][512] (borders zeroed here)
__global__ __launch_bounds__(256) void ln_k(const float* __restrict__ virt, const float* __restrict__ gamma,
                                            const float* __restrict__ beta, ushort* __restrict__ vp) {
    int b = blockIdx.x, t = threadIdx.x;
    float s1 = 0.f, s2 = 0.f;
    for (int p = 0; p < 49; p++) {
        const float* r = virt + ((size_t)p * 256 + b) * 512;
        float a = r[t], c = r[t + 256];
        s1 += a + c;
        s2 += a * a + c * c;
    }
    for (int o = 32; o > 0; o >>= 1) { s1 += __shfl_xor(s1, o); s2 += __shfl_xor(s2, o); }
    __shared__ float red[8];
    int wave = t >> 6, lane = t & 63;
    if (lane == 0) { red[wave] = s1; red[4 + wave] = s2; }
    __syncthreads();
    float S1 = red[0] + red[1] + red[2] + red[3];
    float S2 = red[4] + red[5] + red[6] + red[7];
    float mean = S1 * (1.f / 25088.f);
    float var = S2 * (1.f / 25088.f) - mean * mean;
    float rs = rsqrtf(var + 1e-5f);
    float g0 = gamma[t], b0 = beta[t], g1 = gamma[t + 256], b1 = beta[t + 256];
    for (int p = 0; p < 49; p++) {
        const float* r = virt + ((size_t)p * 256 + b) * 512;
        size_t ob = ((size_t)(b * 9 + p / 7 + 1) * 9 + p % 7 + 1) * 512;
        vp[ob + t] = f2bf(fmaxf((r[t] - mean) * rs * g0 + b0, 0.f));
        vp[ob + t + 256] = f2bf(fmaxf((r[t + 256] - mean) * rs * g1 + b1, 0.f));
    }
#pragma unroll
    for (int e = 0; e < 32; e++) {  // zero padding borders
        int hp, wp;
        if (e < 9) { hp = 0; wp = e; }
        else if (e < 18) { hp = 8; wp = e - 9; }
        else { int e2 = e - 18; hp = 1 + (e2 >> 1); wp = (e2 & 1) ? 8 : 0; }
        size_t ob = ((size_t)(b * 9 + hp) * 9 + wp) * 512;
        vp[ob + t] = 0;
        vp[ob + t + 256] = 0;
    }
}

extern "C" void kernel_launch(void* const* d_in, const int* in_sizes, int n_in,
                              void* d_out, int out_size, void* d_ws, size_t ws_size,
                              hipStream_t stream) {
    const float* status = (const float*)d_in[0];
    const float* rois = (const float*)d_in[1];
    const float* bfeat = (const float*)d_in[2];
    const float* w_red = (const float*)d_in[3];
    const float* w_q = (const float*)d_in[4];
    const float* w_k = (const float*)d_in[5];
    const float* w_v = (const float*)d_in[6];
    const float* w_o = (const float*)d_in[7];
    const float* gamma = (const float*)d_in[8];
    const float* beta = (const float*)d_in[9];
    float* out = (float*)d_out;
    char* ws = (char*)d_ws;

    // workspace layout (overlaid by lifetime), ~191 MB peak
    const size_t OFF_XT1 = 0;                       // 21,233,664  xpad-of-x (later vbufT)
    const size_t OFF_C = 21233664;                  // 95,551,488  x0T (later S/att/virt/q/vpad)
    const size_t OFF_S = OFF_C;                     // 12,845,056
    const size_t OFF_ATT = OFF_C + 12845056;        //  6,422,528
    const size_t OFF_VIRT = OFF_ATT + 6422528;      // 25,690,112
    const size_t OFF_QB = OFF_VIRT + 25690112;      // 12,845,056
    const size_t OFF_VPAD = OFF_QB + 12845056;      // 21,233,664 (ends 79.0MB < 95.5MB)
    const size_t OFF_W1T = OFF_C + 95551488;        // 21,233,664  w1T (later kbuf)
    const size_t OFF_WKVT = OFF_W1T + 21233664;     //  9,437,184
    const size_t OFF_WOT = OFF_WKVT + 9437184;      //  4,718,592
    const size_t OFF_XF = OFF_WOT + 4718592;        // 25,690,112  x f32
    const size_t OFF_VB = OFF_XF + 25690112;        // 12,845,056  vbuf
    const size_t OFF_WSQ = OFF_VB + 12845056;       //    200,704
    const size_t NEED = OFF_WSQ + 200704;           // 190,910,464
    if (ws_size < NEED) return;

    // 1) zero XF (atomic accumulator) + border cells of x0T and xpad(x)
    zero_k<<<1024, 256, 0, stream>>>((uint4*)(ws + OFF_XF), 25690112 / 16);
    border_k<<<18432, 256, 0, stream>>>((ushort*)(ws + OFF_C), 2304, 256 * 32 * 576);
    border_k<<<4096, 256, 0, stream>>>((ushort*)(ws + OFF_XT1), 512, 256 * 32 * 128);
    // 2) cast/layout inputs
    cast_x0_k<<<dim3(4, 256), 256, 0, stream>>>(bfeat, (ushort*)(ws + OFF_C));
    cast_w_k<<<512, 256, 0, stream>>>(w_red, (ushort*)(ws + OFF_W1T), 2304);
    cast_w_k<<<512, 256, 0, stream>>>(w_k, (ushort*)(ws + OFF_WKVT), 512);
    cast_w_k<<<512, 256, 0, stream>>>(w_v, (ushort*)(ws + OFF_WKVT) + (size_t)512 * 9 * 512, 512);
    cast_w_k<<<512, 256, 0, stream>>>(w_o, (ushort*)(ws + OFF_WOT), 512);
    // 3) conv_reduce split-K=2 (atomic into XF), then build xpad bf16
    gemm_bt<1, 0><<<dim3(4, 98, 2), 256, 0, stream>>>(
        (ushort*)(ws + OFF_C), (ushort*)(ws + OFF_W1T),
        (float*)(ws + OFF_XF), nullptr, nullptr,
        12544, 512, 20736, 2304, 9, 2);
    xpad_k<<<dim3(2, 256), 256, 0, stream>>>((float*)(ws + OFF_XF), (ushort*)(ws + OFF_XT1));
    // 4) k & v convs fused (N=1024, K=4608); kbuf overwrites w1T region
    gemm_bt<1, 1><<<dim3(8, 98, 1), 256, 0, stream>>>(
        (ushort*)(ws + OFF_XT1), (ushort*)(ws + OFF_WKVT),
        nullptr, (ushort*)(ws + OFF_W1T), (ushort*)(ws + OFF_VB),
        12544, 1024, 4608, 512, 9, 1);
    // 5) q path (conv of spatially-constant field -> windowed weight sums)
    wsq_k<<<49, 512, 0, stream>>>(w_q, (float*)(ws + OFF_WSQ));
    qgen_k<<<dim3(256, 49), 256, 0, stream>>>(status, rois, (float*)(ws + OFF_WSQ), (ushort*)(ws + OFF_QB));
    // 6) V^T for PV gemm (vbufT overwrites xpad(x) region)
    transpose_v_k<<<dim3(8, 4, 49), 256, 0, stream>>>((ushort*)(ws + OFF_VB), (ushort*)(ws + OFF_XT1));
    // 7) S = (q/sqrt(C)) . k^T  per spatial position
    gemm_bt<0, 2><<<dim3(2, 2, 49), 256, 0, stream>>>(
        (ushort*)(ws + OFF_QB), (ushort*)(ws + OFF_W1T),
        (float*)(ws + OFF_S), nullptr, nullptr, 256, 256, 512, 512, 1, 1);
    // 8) softmax over j
    softmax_k<<<3136, 256, 0, stream>>>((float*)(ws + OFF_S), (ushort*)(ws + OFF_ATT));
    // 9) virt = att @ V
    gemm_bt<0, 3><<<dim3(4, 2, 49), 256, 0, stream>>>(
        (ushort*)(ws + OFF_ATT), (ushort*)(ws + OFF_XT1),
        (float*)(ws + OFF_VIRT), nullptr, nullptr, 256, 512, 256, 256, 1, 1);
    // 10) layernorm + relu -> padded bf16
    ln_k<<<256, 256, 0, stream>>>((float*)(ws + OFF_VIRT), gamma, beta, (ushort*)(ws + OFF_VPAD));
    // 11) out = x + conv(virt, w_out): prefill out with x, then split-K=2 atomic adds
    copy_k<<<1024, 256, 0, stream>>>((const uint4*)(ws + OFF_XF), (uint4*)out, 25690112 / 16);
    gemm_bt<1, 0><<<dim3(4, 98, 2), 256, 0, stream>>>(
        (ushort*)(ws + OFF_VPAD), (ushort*)(ws + OFF_WOT),
        out, nullptr, nullptr,
        12544, 512, 4608, 512, 9, 2);
}

// Round 3
// 1131.858 us; speedup vs baseline: 1.4615x; 1.4615x over previous
//
#include <hip/hip_runtime.h>
#include <stdint.h>

#define AS1 __attribute__((address_space(1)))
#define AS3 __attribute__((address_space(3)))

typedef __bf16 bf16x8 __attribute__((ext_vector_type(8)));
typedef float  f32x4  __attribute__((ext_vector_type(4)));

__device__ __forceinline__ void gl_lds16(const void* g, void* l) {
    __builtin_amdgcn_global_load_lds((AS1 void*)g, (AS3 void*)l, 16, 0, 0);
}

// f32 -> bf16 round-to-nearest-even
__device__ __forceinline__ ushort f2bf(float f) {
    unsigned x = __float_as_uint(f);
    return (ushort)((x + 0x7fffu + ((x >> 16) & 1u)) >> 16);
}

// ---------------------------------------------------------------------------
// GEMM: C[m][n] = sum_k A[m][k] * BT[n][k]   (128x128 tile, BK=32, bf16 MFMA)
// AMODE 0: A flat [m][K]; blockIdx.z = batch (A,B offset by z*M*K / z*N*K)
// AMODE 1: conv gather, m=(b*49+p), k=(s*Cin+ci); blockIdx.z = split-K chunk
//          (ci range [z*Cin/splitZ, (z+1)*Cin/splitZ))
// EPI 0: partials -> OF[(z*M + m)*N + n]  (coalesced, reduced later)
// EPI 1: conv_kv  -> n<512: OU0 = kbuf [p][j][512]; else OU1 = vbuf [p][j][512]
// EPI 2: scores   -> OF[z*256+m][n]  (256 wide)
// EPI 3: PV       -> OF[z*256+m][n]  (512 wide)
// ---------------------------------------------------------------------------
template <int AMODE, int EPI>
__global__ __launch_bounds__(256, 4) void gemm_bt(
    const ushort* __restrict__ A, const ushort* __restrict__ BT,
    float* __restrict__ OF, ushort* __restrict__ OU0, ushort* __restrict__ OU1,
    int M, int N, int K, int Cin, int Ksegs, int splitZ) {
    __shared__ ushort As[128 * 32];
    __shared__ ushort Bs[128 * 32];

    const int t = threadIdx.x;
    const int lane = t & 63;
    const int wave = t >> 6;
    const int wm = wave & 1, wn = wave >> 1;
    const int blockN = blockIdx.x * 128;
    const int blockM = blockIdx.y * 128;
    const int z = blockIdx.z;

    const char* Ab = (const char*)A;
    const char* Bb = (const char*)BT;
    if (AMODE == 0) {
        Ab += (size_t)z * (size_t)M * (size_t)K * 2;
        Bb += (size_t)z * (size_t)N * (size_t)K * 2;
    }

    const int rS = t >> 2;              // staging row 0..63 (and +64)
    const int seg = (t & 3) * 16;       // 16B segment within a 64B K-tile row

    unsigned abase0, abase1;
    if (AMODE == 1) {
        int m0 = blockM + rS, m1 = m0 + 64;
        int b0 = m0 / 49, p0 = m0 % 49;
        int b1 = m1 / 49, p1 = m1 % 49;
        abase0 = (unsigned)(((b0 * 9 + p0 / 7) * 9 + p0 % 7) * Cin);
        abase1 = (unsigned)(((b1 * 9 + p1 / 7) * 9 + p1 % 7) * Cin);
    } else {
        abase0 = (unsigned)((blockM + rS) * K);
        abase1 = abase0 + (unsigned)(64 * K);
    }
    const unsigned bbase0 = (unsigned)((blockN + rS) * K);
    const unsigned bbase1 = bbase0 + (unsigned)(64 * K);

    f32x4 zero = {0.f, 0.f, 0.f, 0.f};
    f32x4 acc[4][4];
    for (int i = 0; i < 4; i++)
        for (int j = 0; j < 4; j++) acc[i][j] = zero;

    const unsigned chunk = (AMODE == 1) ? (unsigned)(Cin / splitZ) : (unsigned)K;
    const unsigned ciBase = (AMODE == 1) ? (unsigned)z * chunk : 0u;
    const int citers = (int)(chunk / 32);
    const int nseg = (AMODE == 1) ? Ksegs : 1;

    for (int s = 0; s < nseg; ++s) {
        const char *aseg0, *aseg1, *bseg0, *bseg1;
        if (AMODE == 1) {
            unsigned shift = (unsigned)(((s / 3) * 9 + (s % 3)) * Cin) + ciBase;
            aseg0 = Ab + (size_t)(abase0 + shift) * 2 + seg;
            aseg1 = Ab + (size_t)(abase1 + shift) * 2 + seg;
            unsigned bshift = (unsigned)(s * Cin) + ciBase;
            bseg0 = Bb + (size_t)(bbase0 + bshift) * 2 + seg;
            bseg1 = Bb + (size_t)(bbase1 + bshift) * 2 + seg;
        } else {
            aseg0 = Ab + (size_t)abase0 * 2 + seg;
            aseg1 = Ab + (size_t)abase1 * 2 + seg;
            bseg0 = Bb + (size_t)bbase0 * 2 + seg;
            bseg1 = Bb + (size_t)bbase1 * 2 + seg;
        }

        for (int ct = 0; ct < citers; ++ct) {
            __syncthreads();  // previous compute done reading LDS
            gl_lds16(aseg0 + ct * 64, (char*)As + t * 16);
            gl_lds16(aseg1 + ct * 64, (char*)As + 4096 + t * 16);
            gl_lds16(bseg0 + ct * 64, (char*)Bs + t * 16);
            gl_lds16(bseg1 + ct * 64, (char*)Bs + 4096 + t * 16);
            __syncthreads();  // staging visible

            const ushort* Ap = As + (wm * 64 + (lane & 15)) * 32 + (lane >> 4) * 8;
            const ushort* Bp = Bs + (wn * 64 + (lane & 15)) * 32 + (lane >> 4) * 8;
            bf16x8 af[4], bfr[4];
#pragma unroll
            for (int i = 0; i < 4; i++) {
                af[i] = *(const bf16x8*)(Ap + i * 16 * 32);
                bfr[i] = *(const bf16x8*)(Bp + i * 16 * 32);
            }
#pragma unroll
            for (int i = 0; i < 4; i++)
#pragma unroll
                for (int j = 0; j < 4; j++)
                    acc[i][j] = __builtin_amdgcn_mfma_f32_16x16x32_bf16(af[i], bfr[j], acc[i][j], 0, 0, 0);
        }
    }

    // epilogue: C/D layout col=lane&15, row=(lane>>4)*4+r  [m89/m91 verified]
    const int mrow = (lane >> 4) * 4;
    const int ncol = lane & 15;
#pragma unroll
    for (int i = 0; i < 4; i++) {
#pragma unroll
        for (int j = 0; j < 4; j++) {
            f32x4 v = acc[i][j];
#pragma unroll
            for (int r = 0; r < 4; r++) {
                int m = blockM + wm * 64 + i * 16 + mrow + r;
                int n = blockN + wn * 64 + j * 16 + ncol;
                float val = v[r];
                if (EPI == 0) {
                    OF[((size_t)z * M + m) * N + n] = val;  // coalesced partial
                } else if (EPI == 1) {
                    int j2 = m / 49, p = m % 49;
                    if (n < 512)
                        OU0[(size_t)(p * 256 + j2) * 512 + n] = f2bf(val);
                    else
                        OU1[(size_t)(p * 256 + j2) * 512 + (n - 512)] = f2bf(val);
                } else if (EPI == 2) {
                    OF[((size_t)z * 256 + m) * 256 + n] = val;
                } else {
                    OF[((size_t)z * 256 + m) * 512 + n] = val;
                }
            }
        }
    }
}

// zero only the 32 border cells of a padded [256][9][9][C] bf16 tensor
__global__ void border_k(ushort* __restrict__ base, int C, int nvec) {
    int id = blockIdx.x * 256 + threadIdx.x;
    if (id >= nvec) return;
    int cpc = C >> 2;
    int c4 = (id % cpc) * 4;
    int r = id / cpc;
    int cell = r & 31, b = r >> 5;
    int hp, wp;
    if (cell < 9) { hp = 0; wp = cell; }
    else if (cell < 18) { hp = 8; wp = cell - 9; }
    else { int e2 = cell - 18; hp = 1 + (e2 >> 1); wp = (e2 & 1) ? 8 : 0; }
    ushort4 zz = {0, 0, 0, 0};
    *(ushort4*)(base + ((size_t)(b * 9 + hp) * 9 + wp) * C + c4) = zz;
}

// reduce1: P0+P1 [m=(b,p)][c] -> XF f32 [b][c][p] (NCHW) + xpad bf16 [b][h+1][w+1][c]
__global__ __launch_bounds__(256) void reduce1_k(const float* __restrict__ P,
                                                 float* __restrict__ XF, ushort* __restrict__ xp) {
    __shared__ float lf[256 * 49];  // [c][p], 50176 B
    int h = blockIdx.x, b = blockIdx.y, t = threadIdx.x;
    const float* p0 = P + ((size_t)b * 49) * 512 + h * 256;
    const float* p1 = p0 + (size_t)12544 * 512;
    for (int e = t; e < 49 * 64; e += 256) {
        int p = e >> 6, c4 = (e & 63) << 2;
        float4 a = *(const float4*)(p0 + (size_t)p * 512 + c4);
        float4 c = *(const float4*)(p1 + (size_t)p * 512 + c4);
        a.x += c.x; a.y += c.y; a.z += c.z; a.w += c.w;
        ushort4 u;
        u.x = f2bf(a.x); u.y = f2bf(a.y); u.z = f2bf(a.z); u.w = f2bf(a.w);
        *(ushort4*)(xp + (size_t)((b * 9 + p / 7 + 1) * 9 + p % 7 + 1) * 512 + h * 256 + c4) = u;
        lf[(c4 + 0) * 49 + p] = a.x;
        lf[(c4 + 1) * 49 + p] = a.y;
        lf[(c4 + 2) * 49 + p] = a.z;
        lf[(c4 + 3) * 49 + p] = a.w;
    }
    __syncthreads();
    float* xfb = XF + (size_t)b * 25088 + h * 12544;  // this half's [c][p]
    for (int e = t; e < 256 * 49; e += 256) xfb[e] = lf[e];
}

// reduce2: out NCHW = XF + P0 + P1 (transposed)
__global__ __launch_bounds__(256) void reduce2_k(const float* __restrict__ P,
                                                 const float* __restrict__ XF, float* __restrict__ out) {
    __shared__ float lf[256 * 49];
    int h = blockIdx.x, b = blockIdx.y, t = threadIdx.x;
    const float* p0 = P + ((size_t)b * 49) * 512 + h * 256;
    const float* p1 = p0 + (size_t)12544 * 512;
    for (int e = t; e < 49 * 64; e += 256) {
        int p = e >> 6, c4 = (e & 63) << 2;
        float4 a = *(const float4*)(p0 + (size_t)p * 512 + c4);
        float4 c = *(const float4*)(p1 + (size_t)p * 512 + c4);
        lf[(c4 + 0) * 49 + p] = a.x + c.x;
        lf[(c4 + 1) * 49 + p] = a.y + c.y;
        lf[(c4 + 2) * 49 + p] = a.z + c.z;
        lf[(c4 + 3) * 49 + p] = a.w + c.w;
    }
    __syncthreads();
    const float* xfb = XF + (size_t)b * 25088 + h * 12544;
    float* ob = out + (size_t)b * 25088 + h * 12544;
    for (int e = t; e < 256 * 49; e += 256) ob[e] = xfb[e] + lf[e];
}

// bbox_featx f32 [b][2304][49] -> x0T bf16 [b][9][9][2304] interior
__global__ __launch_bounds__(256) void cast_x0_k(const float* __restrict__ in, ushort* __restrict__ out) {
    __shared__ ushort tl[576 * 49];  // [ci][p] within tile
    int cit = blockIdx.x, b = blockIdx.y, t = threadIdx.x;
    const float* src = in + ((size_t)b * 2304 + cit * 576) * 49;
    for (int e4 = t; e4 < 7056; e4 += 256) {
        float4 v = *(const float4*)(src + e4 * 4);
        ushort4 u;
        u.x = f2bf(v.x); u.y = f2bf(v.y); u.z = f2bf(v.z); u.w = f2bf(v.w);
        *(ushort4*)(tl + e4 * 4) = u;
    }
    __syncthreads();
    for (int e4 = t; e4 < 7056; e4 += 256) {  // 49 p * 144 c4-groups
        int p = e4 / 144, c4 = (e4 % 144) * 4;
        ushort4 u;
        u.x = tl[c4 * 49 + p]; u.y = tl[(c4 + 1) * 49 + p];
        u.z = tl[(c4 + 2) * 49 + p]; u.w = tl[(c4 + 3) * 49 + p];
        *(ushort4*)(out + (size_t)((b * 9 + p / 7 + 1) * 9 + p % 7 + 1) * 2304 + cit * 576 + c4) = u;
    }
}

// weight f32 [co][Cin][9] -> bf16 [co][9][Cin]  (one block per co)
__global__ void cast_w_k(const float* __restrict__ in, ushort* __restrict__ out, int Cin) {
    __shared__ float lds[256 * 9];
    int co = blockIdx.x, t = threadIdx.x;
    for (int ci0 = 0; ci0 < Cin; ci0 += 256) {
        const float* src = in + ((size_t)co * Cin + ci0 + t) * 9;
#pragma unroll
        for (int j = 0; j < 9; j++) lds[t * 9 + j] = src[j];
        __syncthreads();
#pragma unroll
        for (int s = 0; s < 9; s++) out[((size_t)co * 9 + s) * Cin + ci0 + t] = f2bf(lds[t * 9 + s]);
        __syncthreads();
    }
}

// windowed sums of w_q per spatial pos: WSQ[p][ci][co]
__global__ void wsq_k(const float* __restrict__ wq, float* __restrict__ WSQ) {
    int p = blockIdx.x, co = threadIdx.x;
    int h = p / 7, w = p % 7;
#pragma unroll
    for (int ci = 0; ci < 2; ci++) {
        float a = 0.f;
        for (int kh = 0; kh < 3; kh++) {
            int hi = h + kh - 1;
            if (hi < 0 || hi > 6) continue;
            for (int kw = 0; kw < 3; kw++) {
                int wi = w + kw - 1;
                if (wi < 0 || wi > 6) continue;
                a += wq[(((size_t)co * 2 + ci) * 3 + kh) * 3 + kw];
            }
        }
        WSQ[((size_t)p * 2 + ci) * 512 + co] = a;
    }
}

// q bf16 [p][b][512], scaled by 1/sqrt(512)
__global__ void qgen_k(const float* __restrict__ status, const float* __restrict__ rois,
                       const float* __restrict__ WSQ, ushort* __restrict__ qb) {
    int b = blockIdx.x, p = blockIdx.y, t = threadIdx.x;
    float st0 = status[b * 2], st1 = rois[b * 2 + 1];
    int c = t * 2;
    const float* w0 = WSQ + (size_t)p * 2 * 512;
    const float sc = 0.04419417382415922f;  // 1/sqrt(512)
    float q0 = (st0 * w0[c] + st1 * w0[512 + c]) * sc;
    float q1 = (st0 * w0[c + 1] + st1 * w0[512 + c + 1]) * sc;
    unsigned u = (unsigned)f2bf(q0) | ((unsigned)f2bf(q1) << 16);
    *(unsigned*)(qb + ((size_t)p * 256 + b) * 512 + c) = u;
}

// softmax over rows of 256 (S f32 -> att bf16), one wave per row
__global__ void softmax_k(const float* __restrict__ S, ushort* __restrict__ att) {
    int row = blockIdx.x * 4 + (threadIdx.x >> 6);
    int lane = threadIdx.x & 63;
    const float4 sv = *(const float4*)(S + (size_t)row * 256 + lane * 4);
    float m = fmaxf(fmaxf(sv.x, sv.y), fmaxf(sv.z, sv.w));
    for (int o = 32; o > 0; o >>= 1) m = fmaxf(m, __shfl_xor(m, o));
    float e0 = __expf(sv.x - m), e1 = __expf(sv.y - m);
    float e2 = __expf(sv.z - m), e3 = __expf(sv.w - m);
    float s = e0 + e1 + e2 + e3;
    for (int o = 32; o > 0; o >>= 1) s += __shfl_xor(s, o);
    float inv = 1.f / s;
    ushort4 o4;
    o4.x = f2bf(e0 * inv); o4.y = f2bf(e1 * inv);
    o4.z = f2bf(e2 * inv); o4.w = f2bf(e3 * inv);
    *(ushort4*)(att + (size_t)row * 256 + lane * 4) = o4;
}

// vbuf [p][j][512] -> vbufT [p][512][j] (64x64 LDS tiles)
__global__ void transpose_v_k(const ushort* __restrict__ vb, ushort* __restrict__ vt) {
    __shared__ ushort tl[64][66];
    int p = blockIdx.z, j0 = blockIdx.y * 64, c0 = blockIdx.x * 64;
    int t = threadIdx.x;
#pragma unroll
    for (int i = 0; i < 4; i++) {
        int e = i * 1024 + t * 4;
        int j = e >> 6, c = e & 63;
        ushort4 v = *(const ushort4*)(vb + ((size_t)p * 256 + j0 + j) * 512 + c0 + c);
        tl[j][c] = v.x; tl[j][c + 1] = v.y; tl[j][c + 2] = v.z; tl[j][c + 3] = v.w;
    }
    __syncthreads();
#pragma unroll
    for (int i = 0; i < 4; i++) {
        int e = i * 1024 + t * 4;
        int cc = e >> 6, jj = e & 63;
        ushort4 o;
        o.x = tl[jj][cc]; o.y = tl[jj + 1][cc]; o.z = tl[jj + 2][cc]; o.w = tl[jj + 3][cc];
        *(ushort4*)(vt + ((size_t)p * 512 + c0 + cc) * 256 + j0 + jj) = o;
    }
}

// layernorm over (c,p) per b + gamma/beta + relu -> vpad bf16 [b][9][9][512] (borders zeroed)
__global__ __launch_bounds__(256) void ln_k(const float* __restrict__ virt, const float* __restrict__ gamma,
                                            const float* __restrict__ beta, ushort* __restrict__ vp) {
    int b = blockIdx.x, t = threadIdx.x;
    float s1 = 0.f, s2 = 0.f;
    for (int p = 0; p < 49; p++) {
        const float* r = virt + ((size_t)p * 256 + b) * 512;
        float a = r[t], c = r[t + 256];
        s1 += a + c;
        s2 += a * a + c * c;
    }
    for (int o = 32; o > 0; o >>= 1) { s1 += __shfl_xor(s1, o); s2 += __shfl_xor(s2, o); }
    __shared__ float red[8];
    int wave = t >> 6, lane = t & 63;
    if (lane == 0) { red[wave] = s1; red[4 + wave] = s2; }
    __syncthreads();
    float S1 = red[0] + red[1] + red[2] + red[3];
    float S2 = red[4] + red[5] + red[6] + red[7];
    float mean = S1 * (1.f / 25088.f);
    float var = S2 * (1.f / 25088.f) - mean * mean;
    float rs = rsqrtf(var + 1e-5f);
    float g0 = gamma[t], b0 = beta[t], g1 = gamma[t + 256], b1 = beta[t + 256];
    for (int p = 0; p < 49; p++) {
        const float* r = virt + ((size_t)p * 256 + b) * 512;
        size_t ob = ((size_t)(b * 9 + p / 7 + 1) * 9 + p % 7 + 1) * 512;
        vp[ob + t] = f2bf(fmaxf((r[t] - mean) * rs * g0 + b0, 0.f));
        vp[ob + t + 256] = f2bf(fmaxf((r[t + 256] - mean) * rs * g1 + b1, 0.f));
    }
#pragma unroll
    for (int e = 0; e < 32; e++) {  // zero padding borders
        int hp, wp;
        if (e < 9) { hp = 0; wp = e; }
        else if (e < 18) { hp = 8; wp = e - 9; }
        else { int e2 = e - 18; hp = 1 + (e2 >> 1); wp = (e2 & 1) ? 8 : 0; }
        size_t ob = ((size_t)(b * 9 + hp) * 9 + wp) * 512;
        vp[ob + t] = 0;
        vp[ob + t + 256] = 0;
    }
}

extern "C" void kernel_launch(void* const* d_in, const int* in_sizes, int n_in,
                              void* d_out, int out_size, void* d_ws, size_t ws_size,
                              hipStream_t stream) {
    const float* status = (const float*)d_in[0];
    const float* rois = (const float*)d_in[1];
    const float* bfeat = (const float*)d_in[2];
    const float* w_red = (const float*)d_in[3];
    const float* w_q = (const float*)d_in[4];
    const float* w_k = (const float*)d_in[5];
    const float* w_v = (const float*)d_in[6];
    const float* w_o = (const float*)d_in[7];
    const float* gamma = (const float*)d_in[8];
    const float* beta = (const float*)d_in[9];
    float* out = (float*)d_out;
    char* ws = (char*)d_ws;

    // ---- workspace layout (overlaid by lifetime), 182.5 MB peak ----
    // Region A [0, 51.4MB): split-K partials P0/P1; mid-pipeline hosts
    //   kbuf/vbuf/vbufT/qb; then conv_out partials again.
    const size_t OFF_P = 0;                          // 2 x 25,690,112
    const size_t OFF_KB = 0;                         // 12,845,056 kbuf [p][j][512]
    const size_t OFF_VB = 12845056;                  // 12,845,056 vbuf [p][j][512]
    const size_t OFF_VT = 25690112;                  // 12,845,056 vbufT [p][512][j]
    const size_t OFF_QB = 38535168;                  // 12,845,056 q [p][b][512]
    // Region B [51.4MB, 146.9MB): x0T during conv_reduce; then XF/xpad/S/att/virt/vpad
    const size_t OFF_B = 51380224;
    const size_t OFF_XF = OFF_B;                     // 25,690,112 x f32 NCHW
    const size_t OFF_XPAD = OFF_B + 25690112;        // 21,233,664 xpad bf16 (later vpad)
    const size_t OFF_S = OFF_B + 46923776;           // 12,845,056
    const size_t OFF_ATT = OFF_B + 59768832;         //  6,422,528
    const size_t OFF_VIRT = OFF_B + 66191360;        // 25,690,112 (ends 91.9MB < 95.5MB)
    // Region C [146.9MB, ...): weights
    const size_t OFF_W1T = 146931712;                // 21,233,664
    const size_t OFF_WKVT = OFF_W1T + 21233664;      //  9,437,184
    const size_t OFF_WOT = OFF_WKVT + 9437184;       //  4,718,592
    const size_t OFF_WSQ = OFF_WOT + 4718592;        //    200,704
    const size_t NEED = OFF_WSQ + 200704;            // 182,521,856
    if (ws_size < NEED) return;

    // 1) prep: x0T borders + casts
    border_k<<<18432, 256, 0, stream>>>((ushort*)(ws + OFF_B), 2304, 256 * 32 * 576);
    cast_x0_k<<<dim3(4, 256), 256, 0, stream>>>(bfeat, (ushort*)(ws + OFF_B));
    cast_w_k<<<512, 256, 0, stream>>>(w_red, (ushort*)(ws + OFF_W1T), 2304);
    cast_w_k<<<512, 256, 0, stream>>>(w_k, (ushort*)(ws + OFF_WKVT), 512);
    cast_w_k<<<512, 256, 0, stream>>>(w_v, (ushort*)(ws + OFF_WKVT) + (size_t)512 * 9 * 512, 512);
    cast_w_k<<<512, 256, 0, stream>>>(w_o, (ushort*)(ws + OFF_WOT), 512);
    // 2) conv_reduce split-K=2 -> partials, then reduce -> XF + xpad
    gemm_bt<1, 0><<<dim3(4, 98, 2), 256, 0, stream>>>(
        (ushort*)(ws + OFF_B), (ushort*)(ws + OFF_W1T),
        (float*)(ws + OFF_P), nullptr, nullptr,
        12544, 512, 20736, 2304, 9, 2);
    border_k<<<4096, 256, 0, stream>>>((ushort*)(ws + OFF_XPAD), 512, 256 * 32 * 128);
    reduce1_k<<<dim3(2, 256), 256, 0, stream>>>(
        (const float*)(ws + OFF_P), (float*)(ws + OFF_XF), (ushort*)(ws + OFF_XPAD));
    // 3) k & v convs fused (N=1024, K=4608)
    gemm_bt<1, 1><<<dim3(8, 98, 1), 256, 0, stream>>>(
        (ushort*)(ws + OFF_XPAD), (ushort*)(ws + OFF_WKVT),
        nullptr, (ushort*)(ws + OFF_KB), (ushort*)(ws + OFF_VB),
        12544, 1024, 4608, 512, 9, 1);
    // 4) q path
    wsq_k<<<49, 512, 0, stream>>>(w_q, (float*)(ws + OFF_WSQ));
    qgen_k<<<dim3(256, 49), 256, 0, stream>>>(status, rois, (float*)(ws + OFF_WSQ), (ushort*)(ws + OFF_QB));
    // 5) V^T
    transpose_v_k<<<dim3(8, 4, 49), 256, 0, stream>>>((ushort*)(ws + OFF_VB), (ushort*)(ws + OFF_VT));
    // 6) S = q.k^T per spatial position
    gemm_bt<0, 2><<<dim3(2, 2, 49), 256, 0, stream>>>(
        (ushort*)(ws + OFF_QB), (ushort*)(ws + OFF_KB),
        (float*)(ws + OFF_S), nullptr, nullptr, 256, 256, 512, 512, 1, 1);
    // 7) softmax
    softmax_k<<<3136, 256, 0, stream>>>((float*)(ws + OFF_S), (ushort*)(ws + OFF_ATT));
    // 8) virt = att @ V
    gemm_bt<0, 3><<<dim3(4, 2, 49), 256, 0, stream>>>(
        (ushort*)(ws + OFF_ATT), (ushort*)(ws + OFF_VT),
        (float*)(ws + OFF_VIRT), nullptr, nullptr, 256, 512, 256, 256, 1, 1);
    // 9) layernorm + relu -> vpad (overlays dead xpad slot)
    ln_k<<<256, 256, 0, stream>>>((float*)(ws + OFF_VIRT), gamma, beta, (ushort*)(ws + OFF_XPAD));
    // 10) conv_out split-K=2 -> partials, then out = XF + P0 + P1
    gemm_bt<1, 0><<<dim3(4, 98, 2), 256, 0, stream>>>(
        (ushort*)(ws + OFF_XPAD), (ushort*)(ws + OFF_WOT),
        (float*)(ws + OFF_P), nullptr, nullptr,
        12544, 512, 4608, 512, 9, 2);
    reduce2_k<<<dim3(2, 256), 256, 0, stream>>>(
        (const float*)(ws + OFF_P), (const float*)(ws + OFF_XF), out);
}

// Round 4
// 1092.286 us; speedup vs baseline: 1.5144x; 1.0362x over previous
//
#include <hip/hip_runtime.h>
#include <stdint.h>

#define AS1 __attribute__((address_space(1)))
#define AS3 __attribute__((address_space(3)))

typedef __bf16 bf16x8 __attribute__((ext_vector_type(8)));
typedef float  f32x4  __attribute__((ext_vector_type(4)));

__device__ __forceinline__ void gl_lds16(const void* g, void* l) {
    __builtin_amdgcn_global_load_lds((AS1 void*)g, (AS3 void*)l, 16, 0, 0);
}

// f32 -> bf16 round-to-nearest-even
__device__ __forceinline__ ushort f2bf(float f) {
    unsigned x = __float_as_uint(f);
    return (ushort)((x + 0x7fffu + ((x >> 16) & 1u)) >> 16);
}

// ---------------------------------------------------------------------------
// GEMM: C[m][n] = sum_k A[m][k] * BT[n][k]
// 128x128 tile, BK=64 staged as 2 x 32-K chunks per barrier pair (halves the
// number of vmcnt(0)+barrier drains per FLOP; each chunk keeps the m97 LDS
// layout so bank behavior and the wave-uniform global_load_lds dest hold).
// AMODE 0: A flat [m][K]; blockIdx.z = batch (A,B offset by z*M*K / z*N*K)
// AMODE 1: conv gather, m=(b*49+p), k=(s*Cin+ci); blockIdx.z = split-K chunk
//          (ci range [z*Cin/splitZ, (z+1)*Cin/splitZ))
// EPI 0: partials -> OF[(z*M + m)*N + n]  (coalesced, reduced later)
// EPI 1: conv_kv  -> n<512: OU0 = kbuf [p][j][512]; else OU1 = vbuf [p][j][512]
// EPI 2: scores   -> OF[z*256+m][n]  (256 wide)
// EPI 3: PV       -> OF[z*256+m][n]  (512 wide)
// NOTE: citers (= chunk/32) must be even for the 2x unroll; all call sites
// satisfy this (36 / 16 / 8 / 16 / 8).
// ---------------------------------------------------------------------------
template <int AMODE, int EPI>
__global__ __launch_bounds__(256, 4) void gemm_bt(
    const ushort* __restrict__ A, const ushort* __restrict__ BT,
    float* __restrict__ OF, ushort* __restrict__ OU0, ushort* __restrict__ OU1,
    int M, int N, int K, int Cin, int Ksegs, int splitZ) {
    __shared__ ushort As[128 * 64];  // 2 chunks x (128 rows x 32 k)
    __shared__ ushort Bs[128 * 64];

    const int t = threadIdx.x;
    const int lane = t & 63;
    const int wave = t >> 6;
    const int wm = wave & 1, wn = wave >> 1;
    const int blockN = blockIdx.x * 128;
    const int blockM = blockIdx.y * 128;
    const int z = blockIdx.z;

    const char* Ab = (const char*)A;
    const char* Bb = (const char*)BT;
    if (AMODE == 0) {
        Ab += (size_t)z * (size_t)M * (size_t)K * 2;
        Bb += (size_t)z * (size_t)N * (size_t)K * 2;
    }

    const int rS = t >> 2;              // staging row 0..63 (and +64)
    const int seg = (t & 3) * 16;       // 16B segment within a 64B K-tile row

    unsigned abase0, abase1;
    if (AMODE == 1) {
        int m0 = blockM + rS, m1 = m0 + 64;
        int b0 = m0 / 49, p0 = m0 % 49;
        int b1 = m1 / 49, p1 = m1 % 49;
        abase0 = (unsigned)(((b0 * 9 + p0 / 7) * 9 + p0 % 7) * Cin);
        abase1 = (unsigned)(((b1 * 9 + p1 / 7) * 9 + p1 % 7) * Cin);
    } else {
        abase0 = (unsigned)((blockM + rS) * K);
        abase1 = abase0 + (unsigned)(64 * K);
    }
    const unsigned bbase0 = (unsigned)((blockN + rS) * K);
    const unsigned bbase1 = bbase0 + (unsigned)(64 * K);

    f32x4 zero = {0.f, 0.f, 0.f, 0.f};
    f32x4 acc[4][4];
    for (int i = 0; i < 4; i++)
        for (int j = 0; j < 4; j++) acc[i][j] = zero;

    const unsigned chunk = (AMODE == 1) ? (unsigned)(Cin / splitZ) : (unsigned)K;
    const unsigned ciBase = (AMODE == 1) ? (unsigned)z * chunk : 0u;
    const int citers2 = (int)(chunk / 64);  // double-iters (BK=64)
    const int nseg = (AMODE == 1) ? Ksegs : 1;

    for (int s = 0; s < nseg; ++s) {
        const char *aseg0, *aseg1, *bseg0, *bseg1;
        if (AMODE == 1) {
            unsigned shift = (unsigned)(((s / 3) * 9 + (s % 3)) * Cin) + ciBase;
            aseg0 = Ab + (size_t)(abase0 + shift) * 2 + seg;
            aseg1 = Ab + (size_t)(abase1 + shift) * 2 + seg;
            unsigned bshift = (unsigned)(s * Cin) + ciBase;
            bseg0 = Bb + (size_t)(bbase0 + bshift) * 2 + seg;
            bseg1 = Bb + (size_t)(bbase1 + bshift) * 2 + seg;
        } else {
            aseg0 = Ab + (size_t)abase0 * 2 + seg;
            aseg1 = Ab + (size_t)abase1 * 2 + seg;
            bseg0 = Bb + (size_t)bbase0 * 2 + seg;
            bseg1 = Bb + (size_t)bbase1 * 2 + seg;
        }

        for (int ct = 0; ct < citers2; ++ct) {
            const int o0 = ct * 128;       // byte offset of chunk 0 (32 k = 64 B)
            const int o1 = ct * 128 + 64;  // chunk 1
            __syncthreads();  // previous compute done reading LDS
            gl_lds16(aseg0 + o0, (char*)As + t * 16);
            gl_lds16(aseg1 + o0, (char*)As + 4096 + t * 16);
            gl_lds16(bseg0 + o0, (char*)Bs + t * 16);
            gl_lds16(bseg1 + o0, (char*)Bs + 4096 + t * 16);
            gl_lds16(aseg0 + o1, (char*)As + 8192 + t * 16);
            gl_lds16(aseg1 + o1, (char*)As + 12288 + t * 16);
            gl_lds16(bseg0 + o1, (char*)Bs + 8192 + t * 16);
            gl_lds16(bseg1 + o1, (char*)Bs + 12288 + t * 16);
            __syncthreads();  // staging visible

#pragma unroll
            for (int h = 0; h < 2; ++h) {
                const ushort* Ap = As + h * 4096 + (wm * 64 + (lane & 15)) * 32 + (lane >> 4) * 8;
                const ushort* Bp = Bs + h * 4096 + (wn * 64 + (lane & 15)) * 32 + (lane >> 4) * 8;
                bf16x8 af[4], bfr[4];
#pragma unroll
                for (int i = 0; i < 4; i++) {
                    af[i] = *(const bf16x8*)(Ap + i * 16 * 32);
                    bfr[i] = *(const bf16x8*)(Bp + i * 16 * 32);
                }
#pragma unroll
                for (int i = 0; i < 4; i++)
#pragma unroll
                    for (int j = 0; j < 4; j++)
                        acc[i][j] = __builtin_amdgcn_mfma_f32_16x16x32_bf16(af[i], bfr[j], acc[i][j], 0, 0, 0);
            }
        }
    }

    // epilogue: C/D layout col=lane&15, row=(lane>>4)*4+r  [m89/m91 verified]
    const int mrow = (lane >> 4) * 4;
    const int ncol = lane & 15;
#pragma unroll
    for (int i = 0; i < 4; i++) {
#pragma unroll
        for (int j = 0; j < 4; j++) {
            f32x4 v = acc[i][j];
#pragma unroll
            for (int r = 0; r < 4; r++) {
                int m = blockM + wm * 64 + i * 16 + mrow + r;
                int n = blockN + wn * 64 + j * 16 + ncol;
                float val = v[r];
                if (EPI == 0) {
                    OF[((size_t)z * M + m) * N + n] = val;  // coalesced partial
                } else if (EPI == 1) {
                    int j2 = m / 49, p = m % 49;
                    if (n < 512)
                        OU0[(size_t)(p * 256 + j2) * 512 + n] = f2bf(val);
                    else
                        OU1[(size_t)(p * 256 + j2) * 512 + (n - 512)] = f2bf(val);
                } else if (EPI == 2) {
                    OF[((size_t)z * 256 + m) * 256 + n] = val;
                } else {
                    OF[((size_t)z * 256 + m) * 512 + n] = val;
                }
            }
        }
    }
}

// zero only the 32 border cells of a padded [256][9][9][C] bf16 tensor
__global__ void border_k(ushort* __restrict__ base, int C, int nvec) {
    int id = blockIdx.x * 256 + threadIdx.x;
    if (id >= nvec) return;
    int cpc = C >> 2;
    int c4 = (id % cpc) * 4;
    int r = id / cpc;
    int cell = r & 31, b = r >> 5;
    int hp, wp;
    if (cell < 9) { hp = 0; wp = cell; }
    else if (cell < 18) { hp = 8; wp = cell - 9; }
    else { int e2 = cell - 18; hp = 1 + (e2 >> 1); wp = (e2 & 1) ? 8 : 0; }
    ushort4 zz = {0, 0, 0, 0};
    *(ushort4*)(base + ((size_t)(b * 9 + hp) * 9 + wp) * C + c4) = zz;
}

// reduce1: P0+P1 [m=(b,p)][c] -> XF f32 [b][c][p] (NCHW) + xpad bf16 [b][h+1][w+1][c]
__global__ __launch_bounds__(256) void reduce1_k(const float* __restrict__ P,
                                                 float* __restrict__ XF, ushort* __restrict__ xp) {
    __shared__ float lf[256 * 49];  // [c][p], 50176 B
    int h = blockIdx.x, b = blockIdx.y, t = threadIdx.x;
    const float* p0 = P + ((size_t)b * 49) * 512 + h * 256;
    const float* p1 = p0 + (size_t)12544 * 512;
    for (int e = t; e < 49 * 64; e += 256) {
        int p = e >> 6, c4 = (e & 63) << 2;
        float4 a = *(const float4*)(p0 + (size_t)p * 512 + c4);
        float4 c = *(const float4*)(p1 + (size_t)p * 512 + c4);
        a.x += c.x; a.y += c.y; a.z += c.z; a.w += c.w;
        ushort4 u;
        u.x = f2bf(a.x); u.y = f2bf(a.y); u.z = f2bf(a.z); u.w = f2bf(a.w);
        *(ushort4*)(xp + (size_t)((b * 9 + p / 7 + 1) * 9 + p % 7 + 1) * 512 + h * 256 + c4) = u;
        lf[(c4 + 0) * 49 + p] = a.x;
        lf[(c4 + 1) * 49 + p] = a.y;
        lf[(c4 + 2) * 49 + p] = a.z;
        lf[(c4 + 3) * 49 + p] = a.w;
    }
    __syncthreads();
    float* xfb = XF + (size_t)b * 25088 + h * 12544;  // this half's [c][p]
    for (int e = t; e < 256 * 49; e += 256) xfb[e] = lf[e];
}

// reduce2: out NCHW = XF + P0 + P1 (transposed)
__global__ __launch_bounds__(256) void reduce2_k(const float* __restrict__ P,
                                                 const float* __restrict__ XF, float* __restrict__ out) {
    __shared__ float lf[256 * 49];
    int h = blockIdx.x, b = blockIdx.y, t = threadIdx.x;
    const float* p0 = P + ((size_t)b * 49) * 512 + h * 256;
    const float* p1 = p0 + (size_t)12544 * 512;
    for (int e = t; e < 49 * 64; e += 256) {
        int p = e >> 6, c4 = (e & 63) << 2;
        float4 a = *(const float4*)(p0 + (size_t)p * 512 + c4);
        float4 c = *(const float4*)(p1 + (size_t)p * 512 + c4);
        lf[(c4 + 0) * 49 + p] = a.x + c.x;
        lf[(c4 + 1) * 49 + p] = a.y + c.y;
        lf[(c4 + 2) * 49 + p] = a.z + c.z;
        lf[(c4 + 3) * 49 + p] = a.w + c.w;
    }
    __syncthreads();
    const float* xfb = XF + (size_t)b * 25088 + h * 12544;
    float* ob = out + (size_t)b * 25088 + h * 12544;
    for (int e = t; e < 256 * 49; e += 256) ob[e] = xfb[e] + lf[e];
}

// bbox_featx f32 [b][2304][49] -> x0T bf16 [b][9][9][2304] interior
__global__ __launch_bounds__(256) void cast_x0_k(const float* __restrict__ in, ushort* __restrict__ out) {
    __shared__ ushort tl[576 * 49];  // [ci][p] within tile
    int cit = blockIdx.x, b = blockIdx.y, t = threadIdx.x;
    const float* src = in + ((size_t)b * 2304 + cit * 576) * 49;
    for (int e4 = t; e4 < 7056; e4 += 256) {
        float4 v = *(const float4*)(src + e4 * 4);
        ushort4 u;
        u.x = f2bf(v.x); u.y = f2bf(v.y); u.z = f2bf(v.z); u.w = f2bf(v.w);
        *(ushort4*)(tl + e4 * 4) = u;
    }
    __syncthreads();
    for (int e4 = t; e4 < 7056; e4 += 256) {  // 49 p * 144 c4-groups
        int p = e4 / 144, c4 = (e4 % 144) * 4;
        ushort4 u;
        u.x = tl[c4 * 49 + p]; u.y = tl[(c4 + 1) * 49 + p];
        u.z = tl[(c4 + 2) * 49 + p]; u.w = tl[(c4 + 3) * 49 + p];
        *(ushort4*)(out + (size_t)((b * 9 + p / 7 + 1) * 9 + p % 7 + 1) * 2304 + cit * 576 + c4) = u;
    }
}

// weight f32 [co][Cin][9] -> bf16 [co][9][Cin]  (one block per co)
__global__ void cast_w_k(const float* __restrict__ in, ushort* __restrict__ out, int Cin) {
    __shared__ float lds[256 * 9];
    int co = blockIdx.x, t = threadIdx.x;
    for (int ci0 = 0; ci0 < Cin; ci0 += 256) {
        const float* src = in + ((size_t)co * Cin + ci0 + t) * 9;
#pragma unroll
        for (int j = 0; j < 9; j++) lds[t * 9 + j] = src[j];
        __syncthreads();
#pragma unroll
        for (int s = 0; s < 9; s++) out[((size_t)co * 9 + s) * Cin + ci0 + t] = f2bf(lds[t * 9 + s]);
        __syncthreads();
    }
}

// windowed sums of w_q per spatial pos: WSQ[p][ci][co]
__global__ void wsq_k(const float* __restrict__ wq, float* __restrict__ WSQ) {
    int p = blockIdx.x, co = threadIdx.x;
    int h = p / 7, w = p % 7;
#pragma unroll
    for (int ci = 0; ci < 2; ci++) {
        float a = 0.f;
        for (int kh = 0; kh < 3; kh++) {
            int hi = h + kh - 1;
            if (hi < 0 || hi > 6) continue;
            for (int kw = 0; kw < 3; kw++) {
                int wi = w + kw - 1;
                if (wi < 0 || wi > 6) continue;
                a += wq[(((size_t)co * 2 + ci) * 3 + kh) * 3 + kw];
            }
        }
        WSQ[((size_t)p * 2 + ci) * 512 + co] = a;
    }
}

// q bf16 [p][b][512], scaled by 1/sqrt(512)
__global__ void qgen_k(const float* __restrict__ status, const float* __restrict__ rois,
                       const float* __restrict__ WSQ, ushort* __restrict__ qb) {
    int b = blockIdx.x, p = blockIdx.y, t = threadIdx.x;
    float st0 = status[b * 2], st1 = rois[b * 2 + 1];
    int c = t * 2;
    const float* w0 = WSQ + (size_t)p * 2 * 512;
    const float sc = 0.04419417382415922f;  // 1/sqrt(512)
    float q0 = (st0 * w0[c] + st1 * w0[512 + c]) * sc;
    float q1 = (st0 * w0[c + 1] + st1 * w0[512 + c + 1]) * sc;
    unsigned u = (unsigned)f2bf(q0) | ((unsigned)f2bf(q1) << 16);
    *(unsigned*)(qb + ((size_t)p * 256 + b) * 512 + c) = u;
}

// softmax over rows of 256 (S f32 -> att bf16), one wave per row
__global__ void softmax_k(const float* __restrict__ S, ushort* __restrict__ att) {
    int row = blockIdx.x * 4 + (threadIdx.x >> 6);
    int lane = threadIdx.x & 63;
    const float4 sv = *(const float4*)(S + (size_t)row * 256 + lane * 4);
    float m = fmaxf(fmaxf(sv.x, sv.y), fmaxf(sv.z, sv.w));
    for (int o = 32; o > 0; o >>= 1) m = fmaxf(m, __shfl_xor(m, o));
    float e0 = __expf(sv.x - m), e1 = __expf(sv.y - m);
    float e2 = __expf(sv.z - m), e3 = __expf(sv.w - m);
    float s = e0 + e1 + e2 + e3;
    for (int o = 32; o > 0; o >>= 1) s += __shfl_xor(s, o);
    float inv = 1.f / s;
    ushort4 o4;
    o4.x = f2bf(e0 * inv); o4.y = f2bf(e1 * inv);
    o4.z = f2bf(e2 * inv); o4.w = f2bf(e3 * inv);
    *(ushort4*)(att + (size_t)row * 256 + lane * 4) = o4;
}

// vbuf [p][j][512] -> vbufT [p][512][j] (64x64 LDS tiles)
__global__ void transpose_v_k(const ushort* __restrict__ vb, ushort* __restrict__ vt) {
    __shared__ ushort tl[64][66];
    int p = blockIdx.z, j0 = blockIdx.y * 64, c0 = blockIdx.x * 64;
    int t = threadIdx.x;
#pragma unroll
    for (int i = 0; i < 4; i++) {
        int e = i * 1024 + t * 4;
        int j = e >> 6, c = e & 63;
        ushort4 v = *(const ushort4*)(vb + ((size_t)p * 256 + j0 + j) * 512 + c0 + c);
        tl[j][c] = v.x; tl[j][c + 1] = v.y; tl[j][c + 2] = v.z; tl[j][c + 3] = v.w;
    }
    __syncthreads();
#pragma unroll
    for (int i = 0; i < 4; i++) {
        int e = i * 1024 + t * 4;
        int cc = e >> 6, jj = e & 63;
        ushort4 o;
        o.x = tl[jj][cc]; o.y = tl[jj + 1][cc]; o.z = tl[jj + 2][cc]; o.w = tl[jj + 3][cc];
        *(ushort4*)(vt + ((size_t)p * 512 + c0 + cc) * 256 + j0 + jj) = o;
    }
}

// layernorm over (c,p) per b + gamma/beta + relu -> vpad bf16 [b][9][9][512] (borders zeroed)
__global__ __launch_bounds__(256) void ln_k(const float* __restrict__ virt, const float* __restrict__ gamma,
                                            const float* __restrict__ beta, ushort* __restrict__ vp) {
    int b = blockIdx.x, t = threadIdx.x;
    float s1 = 0.f, s2 = 0.f;
    for (int p = 0; p < 49; p++) {
        const float* r = virt + ((size_t)p * 256 + b) * 512;
        float a = r[t], c = r[t + 256];
        s1 += a + c;
        s2 += a * a + c * c;
    }
    for (int o = 32; o > 0; o >>= 1) { s1 += __shfl_xor(s1, o); s2 += __shfl_xor(s2, o); }
    __shared__ float red[8];
    int wave = t >> 6, lane = t & 63;
    if (lane == 0) { red[wave] = s1; red[4 + wave] = s2; }
    __syncthreads();
    float S1 = red[0] + red[1] + red[2] + red[3];
    float S2 = red[4] + red[5] + red[6] + red[7];
    float mean = S1 * (1.f / 25088.f);
    float var = S2 * (1.f / 25088.f) - mean * mean;
    float rs = rsqrtf(var + 1e-5f);
    float g0 = gamma[t], b0 = beta[t], g1 = gamma[t + 256], b1 = beta[t + 256];
    for (int p = 0; p < 49; p++) {
        const float* r = virt + ((size_t)p * 256 + b) * 512;
        size_t ob = ((size_t)(b * 9 + p / 7 + 1) * 9 + p % 7 + 1) * 512;
        vp[ob + t] = f2bf(fmaxf((r[t] - mean) * rs * g0 + b0, 0.f));
        vp[ob + t + 256] = f2bf(fmaxf((r[t + 256] - mean) * rs * g1 + b1, 0.f));
    }
#pragma unroll
    for (int e = 0; e < 32; e++) {  // zero padding borders
        int hp, wp;
        if (e < 9) { hp = 0; wp = e; }
        else if (e < 18) { hp = 8; wp = e - 9; }
        else { int e2 = e - 18; hp = 1 + (e2 >> 1); wp = (e2 & 1) ? 8 : 0; }
        size_t ob = ((size_t)(b * 9 + hp) * 9 + wp) * 512;
        vp[ob + t] = 0;
        vp[ob + t + 256] = 0;
    }
}

extern "C" void kernel_launch(void* const* d_in, const int* in_sizes, int n_in,
                              void* d_out, int out_size, void* d_ws, size_t ws_size,
                              hipStream_t stream) {
    const float* status = (const float*)d_in[0];
    const float* rois = (const float*)d_in[1];
    const float* bfeat = (const float*)d_in[2];
    const float* w_red = (const float*)d_in[3];
    const float* w_q = (const float*)d_in[4];
    const float* w_k = (const float*)d_in[5];
    const float* w_v = (const float*)d_in[6];
    const float* w_o = (const float*)d_in[7];
    const float* gamma = (const float*)d_in[8];
    const float* beta = (const float*)d_in[9];
    float* out = (float*)d_out;
    char* ws = (char*)d_ws;

    // ---- workspace layout (overlaid by lifetime), 182.5 MB peak ----
    const size_t OFF_P = 0;                          // 2 x 25,690,112 split-K partials
    const size_t OFF_KB = 0;                         // 12,845,056 kbuf [p][j][512]
    const size_t OFF_VB = 12845056;                  // 12,845,056 vbuf [p][j][512]
    const size_t OFF_VT = 25690112;                  // 12,845,056 vbufT [p][512][j]
    const size_t OFF_QB = 38535168;                  // 12,845,056 q [p][b][512]
    const size_t OFF_B = 51380224;                   // x0T during conv_reduce; then:
    const size_t OFF_XF = OFF_B;                     // 25,690,112 x f32 NCHW
    const size_t OFF_XPAD = OFF_B + 25690112;        // 21,233,664 xpad bf16 (later vpad)
    const size_t OFF_S = OFF_B + 46923776;           // 12,845,056
    const size_t OFF_ATT = OFF_B + 59768832;         //  6,422,528
    const size_t OFF_VIRT = OFF_B + 66191360;        // 25,690,112
    const size_t OFF_W1T = 146931712;                // 21,233,664
    const size_t OFF_WKVT = OFF_W1T + 21233664;      //  9,437,184
    const size_t OFF_WOT = OFF_WKVT + 9437184;       //  4,718,592
    const size_t OFF_WSQ = OFF_WOT + 4718592;        //    200,704
    const size_t NEED = OFF_WSQ + 200704;            // 182,521,856
    if (ws_size < NEED) return;

    // 1) prep: x0T borders + casts
    border_k<<<18432, 256, 0, stream>>>((ushort*)(ws + OFF_B), 2304, 256 * 32 * 576);
    cast_x0_k<<<dim3(4, 256), 256, 0, stream>>>(bfeat, (ushort*)(ws + OFF_B));
    cast_w_k<<<512, 256, 0, stream>>>(w_red, (ushort*)(ws + OFF_W1T), 2304);
    cast_w_k<<<512, 256, 0, stream>>>(w_k, (ushort*)(ws + OFF_WKVT), 512);
    cast_w_k<<<512, 256, 0, stream>>>(w_v, (ushort*)(ws + OFF_WKVT) + (size_t)512 * 9 * 512, 512);
    cast_w_k<<<512, 256, 0, stream>>>(w_o, (ushort*)(ws + OFF_WOT), 512);
    // 2) conv_reduce split-K=2 -> partials, then reduce -> XF + xpad
    gemm_bt<1, 0><<<dim3(4, 98, 2), 256, 0, stream>>>(
        (ushort*)(ws + OFF_B), (ushort*)(ws + OFF_W1T),
        (float*)(ws + OFF_P), nullptr, nullptr,
        12544, 512, 20736, 2304, 9, 2);
    border_k<<<4096, 256, 0, stream>>>((ushort*)(ws + OFF_XPAD), 512, 256 * 32 * 128);
    reduce1_k<<<dim3(2, 256), 256, 0, stream>>>(
        (const float*)(ws + OFF_P), (float*)(ws + OFF_XF), (ushort*)(ws + OFF_XPAD));
    // 3) k & v convs fused (N=1024, K=4608)
    gemm_bt<1, 1><<<dim3(8, 98, 1), 256, 0, stream>>>(
        (ushort*)(ws + OFF_XPAD), (ushort*)(ws + OFF_WKVT),
        nullptr, (ushort*)(ws + OFF_KB), (ushort*)(ws + OFF_VB),
        12544, 1024, 4608, 512, 9, 1);
    // 4) q path
    wsq_k<<<49, 512, 0, stream>>>(w_q, (float*)(ws + OFF_WSQ));
    qgen_k<<<dim3(256, 49), 256, 0, stream>>>(status, rois, (float*)(ws + OFF_WSQ), (ushort*)(ws + OFF_QB));
    // 5) V^T
    transpose_v_k<<<dim3(8, 4, 49), 256, 0, stream>>>((ushort*)(ws + OFF_VB), (ushort*)(ws + OFF_VT));
    // 6) S = q.k^T per spatial position
    gemm_bt<0, 2><<<dim3(2, 2, 49), 256, 0, stream>>>(
        (ushort*)(ws + OFF_QB), (ushort*)(ws + OFF_KB),
        (float*)(ws + OFF_S), nullptr, nullptr, 256, 256, 512, 512, 1, 1);
    // 7) softmax
    softmax_k<<<3136, 256, 0, stream>>>((float*)(ws + OFF_S), (ushort*)(ws + OFF_ATT));
    // 8) virt = att @ V
    gemm_bt<0, 3><<<dim3(4, 2, 49), 256, 0, stream>>>(
        (ushort*)(ws + OFF_ATT), (ushort*)(ws + OFF_VT),
        (float*)(ws + OFF_VIRT), nullptr, nullptr, 256, 512, 256, 256, 1, 1);
    // 9) layernorm + relu -> vpad (overlays dead xpad slot)
    ln_k<<<256, 256, 0, stream>>>((float*)(ws + OFF_VIRT), gamma, beta, (ushort*)(ws + OFF_XPAD));
    // 10) conv_out split-K=2 -> partials, then out = XF + P0 + P1
    gemm_bt<1, 0><<<dim3(4, 98, 2), 256, 0, stream>>>(
        (ushort*)(ws + OFF_XPAD), (ushort*)(ws + OFF_WOT),
        (float*)(ws + OFF_P), nullptr, nullptr,
        12544, 512, 4608, 512, 9, 2);
    reduce2_k<<<dim3(2, 256), 256, 0, stream>>>(
        (const float*)(ws + OFF_P), (const float*)(ws + OFF_XF), out);
}

// Round 5
// 995.008 us; speedup vs baseline: 1.6625x; 1.0978x over previous
//
#include <hip/hip_runtime.h>
#include <stdint.h>

#define AS1 __attribute__((address_space(1)))
#define AS3 __attribute__((address_space(3)))

typedef __bf16 bf16x8 __attribute__((ext_vector_type(8)));
typedef float  f32x4  __attribute__((ext_vector_type(4)));

__device__ __forceinline__ void gl_lds16(const void* g, void* l) {
    __builtin_amdgcn_global_load_lds((AS1 void*)g, (AS3 void*)l, 16, 0, 0);
}

// f32 -> bf16 round-to-nearest-even
__device__ __forceinline__ ushort f2bf(float f) {
    unsigned x = __float_as_uint(f);
    return (ushort)((x + 0x7fffu + ((x >> 16) & 1u)) >> 16);
}
__device__ __forceinline__ float bf2f(ushort u) {
    return __uint_as_float((unsigned)u << 16);
}

// ---------------------------------------------------------------------------
// GEMM: C[m][n] = sum_k A[m][k] * BT[n][k]
// 128x128 tile, BK=64 staged as 2 x 32-K chunks per barrier pair.
// AMODE 0: A flat [m][K]; blockIdx.z = batch (A,B offset by z*M*K / z*N*K)
// AMODE 1: conv gather, m=(b*49+p), k=(s*Cin+ci); blockIdx.z = split-K chunk
//          (ci range [z*Cin/splitZ, (z+1)*Cin/splitZ)); chunk must be %64==0
// EPI 0: bf16 partials -> OU0[(z*M + m)*N + n]  (coalesced, reduced later)
// EPI 2: scores -> OF[z*256+m][n]  (256 wide, f32)
// EPI 3: PV     -> OU0[z*256+m][n] (512 wide, bf16)
// ---------------------------------------------------------------------------
template <int AMODE, int EPI>
__global__ __launch_bounds__(256, 4) void gemm_bt(
    const ushort* __restrict__ A, const ushort* __restrict__ BT,
    float* __restrict__ OF, ushort* __restrict__ OU0,
    int M, int N, int K, int Cin, int Ksegs, int splitZ) {
    __shared__ ushort As[128 * 64];  // 2 chunks x (128 rows x 32 k)
    __shared__ ushort Bs[128 * 64];

    const int t = threadIdx.x;
    const int lane = t & 63;
    const int wave = t >> 6;
    const int wm = wave & 1, wn = wave >> 1;
    const int blockN = blockIdx.x * 128;
    const int blockM = blockIdx.y * 128;
    const int z = blockIdx.z;

    const char* Ab = (const char*)A;
    const char* Bb = (const char*)BT;
    if (AMODE == 0) {
        Ab += (size_t)z * (size_t)M * (size_t)K * 2;
        Bb += (size_t)z * (size_t)N * (size_t)K * 2;
    }

    const int rS = t >> 2;              // staging row 0..63 (and +64)
    const int seg = (t & 3) * 16;       // 16B segment within a 64B K-tile row

    unsigned abase0, abase1;
    if (AMODE == 1) {
        int m0 = blockM + rS, m1 = m0 + 64;
        int b0 = m0 / 49, p0 = m0 % 49;
        int b1 = m1 / 49, p1 = m1 % 49;
        abase0 = (unsigned)(((b0 * 9 + p0 / 7) * 9 + p0 % 7) * Cin);
        abase1 = (unsigned)(((b1 * 9 + p1 / 7) * 9 + p1 % 7) * Cin);
    } else {
        abase0 = (unsigned)((blockM + rS) * K);
        abase1 = abase0 + (unsigned)(64 * K);
    }
    const unsigned bbase0 = (unsigned)((blockN + rS) * K);
    const unsigned bbase1 = bbase0 + (unsigned)(64 * K);

    f32x4 zero = {0.f, 0.f, 0.f, 0.f};
    f32x4 acc[4][4];
    for (int i = 0; i < 4; i++)
        for (int j = 0; j < 4; j++) acc[i][j] = zero;

    const unsigned chunk = (AMODE == 1) ? (unsigned)(Cin / splitZ) : (unsigned)K;
    const unsigned ciBase = (AMODE == 1) ? (unsigned)z * chunk : 0u;
    const int citers2 = (int)(chunk / 64);  // BK=64 iters
    const int nseg = (AMODE == 1) ? Ksegs : 1;

    for (int s = 0; s < nseg; ++s) {
        const char *aseg0, *aseg1, *bseg0, *bseg1;
        if (AMODE == 1) {
            unsigned shift = (unsigned)(((s / 3) * 9 + (s % 3)) * Cin) + ciBase;
            aseg0 = Ab + (size_t)(abase0 + shift) * 2 + seg;
            aseg1 = Ab + (size_t)(abase1 + shift) * 2 + seg;
            unsigned bshift = (unsigned)(s * Cin) + ciBase;
            bseg0 = Bb + (size_t)(bbase0 + bshift) * 2 + seg;
            bseg1 = Bb + (size_t)(bbase1 + bshift) * 2 + seg;
        } else {
            aseg0 = Ab + (size_t)abase0 * 2 + seg;
            aseg1 = Ab + (size_t)abase1 * 2 + seg;
            bseg0 = Bb + (size_t)bbase0 * 2 + seg;
            bseg1 = Bb + (size_t)bbase1 * 2 + seg;
        }

        for (int ct = 0; ct < citers2; ++ct) {
            const int o0 = ct * 128;       // chunk 0 (32 k = 64 B)
            const int o1 = ct * 128 + 64;  // chunk 1
            __syncthreads();  // previous compute done reading LDS
            gl_lds16(aseg0 + o0, (char*)As + t * 16);
            gl_lds16(aseg1 + o0, (char*)As + 4096 + t * 16);
            gl_lds16(bseg0 + o0, (char*)Bs + t * 16);
            gl_lds16(bseg1 + o0, (char*)Bs + 4096 + t * 16);
            gl_lds16(aseg0 + o1, (char*)As + 8192 + t * 16);
            gl_lds16(aseg1 + o1, (char*)As + 12288 + t * 16);
            gl_lds16(bseg0 + o1, (char*)Bs + 8192 + t * 16);
            gl_lds16(bseg1 + o1, (char*)Bs + 12288 + t * 16);
            __syncthreads();  // staging visible

#pragma unroll
            for (int h = 0; h < 2; ++h) {
                const ushort* Ap = As + h * 4096 + (wm * 64 + (lane & 15)) * 32 + (lane >> 4) * 8;
                const ushort* Bp = Bs + h * 4096 + (wn * 64 + (lane & 15)) * 32 + (lane >> 4) * 8;
                bf16x8 af[4], bfr[4];
#pragma unroll
                for (int i = 0; i < 4; i++) {
                    af[i] = *(const bf16x8*)(Ap + i * 16 * 32);
                    bfr[i] = *(const bf16x8*)(Bp + i * 16 * 32);
                }
#pragma unroll
                for (int i = 0; i < 4; i++)
#pragma unroll
                    for (int j = 0; j < 4; j++)
                        acc[i][j] = __builtin_amdgcn_mfma_f32_16x16x32_bf16(af[i], bfr[j], acc[i][j], 0, 0, 0);
            }
        }
    }

    // epilogue: C/D layout col=lane&15, row=(lane>>4)*4+r  [m89/m91 verified]
    const int mrow = (lane >> 4) * 4;
    const int ncol = lane & 15;
#pragma unroll
    for (int i = 0; i < 4; i++) {
#pragma unroll
        for (int j = 0; j < 4; j++) {
            f32x4 v = acc[i][j];
#pragma unroll
            for (int r = 0; r < 4; r++) {
                int m = blockM + wm * 64 + i * 16 + mrow + r;
                int n = blockN + wn * 64 + j * 16 + ncol;
                float val = v[r];
                if (EPI == 0) {
                    OU0[((size_t)z * M + m) * N + n] = f2bf(val);
                } else if (EPI == 2) {
                    OF[((size_t)z * 256 + m) * 256 + n] = val;
                } else {
                    OU0[((size_t)z * 256 + m) * 512 + n] = f2bf(val);
                }
            }
        }
    }
}

// zero only the 32 border cells of a padded [256][9][9][C] bf16 tensor
__global__ void border_k(ushort* __restrict__ base, int C, int nvec) {
    int id = blockIdx.x * 256 + threadIdx.x;
    if (id >= nvec) return;
    int cpc = C >> 2;
    int c4 = (id % cpc) * 4;
    int r = id / cpc;
    int cell = r & 31, b = r >> 5;
    int hp, wp;
    if (cell < 9) { hp = 0; wp = cell; }
    else if (cell < 18) { hp = 8; wp = cell - 9; }
    else { int e2 = cell - 18; hp = 1 + (e2 >> 1); wp = (e2 & 1) ? 8 : 0; }
    ushort4 zz = {0, 0, 0, 0};
    *(ushort4*)(base + ((size_t)(b * 9 + hp) * 9 + wp) * C + c4) = zz;
}

// reduce1: sum 4 bf16 partials [z][m=(b,p)][512] -> XF f32 [b][c][p] + xpad bf16
__global__ __launch_bounds__(256) void reduce1_k(const ushort* __restrict__ P,
                                                 float* __restrict__ XF, ushort* __restrict__ xp) {
    __shared__ float lf[256 * 49];  // [c][p]
    int h = blockIdx.x, b = blockIdx.y, t = threadIdx.x;
    const size_t zs = (size_t)12544 * 512;
    const ushort* base = P + ((size_t)b * 49) * 512 + h * 256;
    for (int e = t; e < 49 * 64; e += 256) {
        int p = e >> 6, c4 = (e & 63) << 2;
        float s0 = 0.f, s1 = 0.f, s2 = 0.f, s3 = 0.f;
#pragma unroll
        for (int z = 0; z < 4; z++) {
            ushort4 u = *(const ushort4*)(base + zs * z + (size_t)p * 512 + c4);
            s0 += bf2f(u.x); s1 += bf2f(u.y); s2 += bf2f(u.z); s3 += bf2f(u.w);
        }
        ushort4 o;
        o.x = f2bf(s0); o.y = f2bf(s1); o.z = f2bf(s2); o.w = f2bf(s3);
        *(ushort4*)(xp + (size_t)((b * 9 + p / 7 + 1) * 9 + p % 7 + 1) * 512 + h * 256 + c4) = o;
        lf[(c4 + 0) * 49 + p] = s0;
        lf[(c4 + 1) * 49 + p] = s1;
        lf[(c4 + 2) * 49 + p] = s2;
        lf[(c4 + 3) * 49 + p] = s3;
    }
    __syncthreads();
    float* xfb = XF + (size_t)b * 25088 + h * 12544;
    for (int e = t; e < 256 * 49; e += 256) xfb[e] = lf[e];
}

// reduce2: out NCHW = XF + sum of 4 bf16 partials (transposed)
__global__ __launch_bounds__(256) void reduce2_k(const ushort* __restrict__ P,
                                                 const float* __restrict__ XF, float* __restrict__ out) {
    __shared__ float lf[256 * 49];
    int h = blockIdx.x, b = blockIdx.y, t = threadIdx.x;
    const size_t zs = (size_t)12544 * 512;
    const ushort* base = P + ((size_t)b * 49) * 512 + h * 256;
    for (int e = t; e < 49 * 64; e += 256) {
        int p = e >> 6, c4 = (e & 63) << 2;
        float s0 = 0.f, s1 = 0.f, s2 = 0.f, s3 = 0.f;
#pragma unroll
        for (int z = 0; z < 4; z++) {
            ushort4 u = *(const ushort4*)(base + zs * z + (size_t)p * 512 + c4);
            s0 += bf2f(u.x); s1 += bf2f(u.y); s2 += bf2f(u.z); s3 += bf2f(u.w);
        }
        lf[(c4 + 0) * 49 + p] = s0;
        lf[(c4 + 1) * 49 + p] = s1;
        lf[(c4 + 2) * 49 + p] = s2;
        lf[(c4 + 3) * 49 + p] = s3;
    }
    __syncthreads();
    const float* xfb = XF + (size_t)b * 25088 + h * 12544;
    float* ob = out + (size_t)b * 25088 + h * 12544;
    for (int e = t; e < 256 * 49; e += 256) ob[e] = xfb[e] + lf[e];
}

// reduce_kv: sum 2 bf16 partials [z][m][1024] -> kbuf [p][j][512] + vbuf [p][j][512]
__global__ void reduce_kv_k(const ushort* __restrict__ P,
                            ushort* __restrict__ kb, ushort* __restrict__ vb) {
    int id = blockIdx.x * 256 + threadIdx.x;  // 12544 * 128 items
    int n8 = id & 127, m = id >> 7;
    int b = m / 49, p = m % 49;
    const ushort* p0 = P + (size_t)m * 1024 + n8 * 8;
    const ushort* p1 = p0 + (size_t)12544 * 1024;
    ushort4 a0 = *(const ushort4*)p0, a1 = *(const ushort4*)(p0 + 4);
    ushort4 b0 = *(const ushort4*)p1, b1 = *(const ushort4*)(p1 + 4);
    ushort4 o0, o1;
    o0.x = f2bf(bf2f(a0.x) + bf2f(b0.x)); o0.y = f2bf(bf2f(a0.y) + bf2f(b0.y));
    o0.z = f2bf(bf2f(a0.z) + bf2f(b0.z)); o0.w = f2bf(bf2f(a0.w) + bf2f(b0.w));
    o1.x = f2bf(bf2f(a1.x) + bf2f(b1.x)); o1.y = f2bf(bf2f(a1.y) + bf2f(b1.y));
    o1.z = f2bf(bf2f(a1.z) + bf2f(b1.z)); o1.w = f2bf(bf2f(a1.w) + bf2f(b1.w));
    size_t dst = ((size_t)p * 256 + b) * 512;
    ushort* o = (n8 < 64) ? (kb + dst + n8 * 8) : (vb + dst + (n8 - 64) * 8);
    *(ushort4*)o = o0;
    *(ushort4*)(o + 4) = o1;
}

// bbox_featx f32 [b][2304][49] -> x0T bf16 [b][9][9][2304] interior
__global__ __launch_bounds__(256) void cast_x0_k(const float* __restrict__ in, ushort* __restrict__ out) {
    __shared__ ushort tl[576 * 49];  // [ci][p] within tile
    int cit = blockIdx.x, b = blockIdx.y, t = threadIdx.x;
    const float* src = in + ((size_t)b * 2304 + cit * 576) * 49;
    for (int e4 = t; e4 < 7056; e4 += 256) {
        float4 v = *(const float4*)(src + e4 * 4);
        ushort4 u;
        u.x = f2bf(v.x); u.y = f2bf(v.y); u.z = f2bf(v.z); u.w = f2bf(v.w);
        *(ushort4*)(tl + e4 * 4) = u;
    }
    __syncthreads();
    for (int e4 = t; e4 < 7056; e4 += 256) {  // 49 p * 144 c4-groups
        int p = e4 / 144, c4 = (e4 % 144) * 4;
        ushort4 u;
        u.x = tl[c4 * 49 + p]; u.y = tl[(c4 + 1) * 49 + p];
        u.z = tl[(c4 + 2) * 49 + p]; u.w = tl[(c4 + 3) * 49 + p];
        *(ushort4*)(out + (size_t)((b * 9 + p / 7 + 1) * 9 + p % 7 + 1) * 2304 + cit * 576 + c4) = u;
    }
}

// weight f32 [co][Cin][9] -> bf16 [co][9][Cin]  (one block per co)
__global__ void cast_w_k(const float* __restrict__ in, ushort* __restrict__ out, int Cin) {
    __shared__ float lds[256 * 9];
    int co = blockIdx.x, t = threadIdx.x;
    for (int ci0 = 0; ci0 < Cin; ci0 += 256) {
        const float* src = in + ((size_t)co * Cin + ci0 + t) * 9;
#pragma unroll
        for (int j = 0; j < 9; j++) lds[t * 9 + j] = src[j];
        __syncthreads();
#pragma unroll
        for (int s = 0; s < 9; s++) out[((size_t)co * 9 + s) * Cin + ci0 + t] = f2bf(lds[t * 9 + s]);
        __syncthreads();
    }
}

// windowed sums of w_q per spatial pos: WSQ[p][ci][co]
__global__ void wsq_k(const float* __restrict__ wq, float* __restrict__ WSQ) {
    int p = blockIdx.x, co = threadIdx.x;
    int h = p / 7, w = p % 7;
#pragma unroll
    for (int ci = 0; ci < 2; ci++) {
        float a = 0.f;
        for (int kh = 0; kh < 3; kh++) {
            int hi = h + kh - 1;
            if (hi < 0 || hi > 6) continue;
            for (int kw = 0; kw < 3; kw++) {
                int wi = w + kw - 1;
                if (wi < 0 || wi > 6) continue;
                a += wq[(((size_t)co * 2 + ci) * 3 + kh) * 3 + kw];
            }
        }
        WSQ[((size_t)p * 2 + ci) * 512 + co] = a;
    }
}

// q bf16 [p][b][512], scaled by 1/sqrt(512)
__global__ void qgen_k(const float* __restrict__ status, const float* __restrict__ rois,
                       const float* __restrict__ WSQ, ushort* __restrict__ qb) {
    int b = blockIdx.x, p = blockIdx.y, t = threadIdx.x;
    float st0 = status[b * 2], st1 = rois[b * 2 + 1];
    int c = t * 2;
    const float* w0 = WSQ + (size_t)p * 2 * 512;
    const float sc = 0.04419417382415922f;  // 1/sqrt(512)
    float q0 = (st0 * w0[c] + st1 * w0[512 + c]) * sc;
    float q1 = (st0 * w0[c + 1] + st1 * w0[512 + c + 1]) * sc;
    unsigned u = (unsigned)f2bf(q0) | ((unsigned)f2bf(q1) << 16);
    *(unsigned*)(qb + ((size_t)p * 256 + b) * 512 + c) = u;
}

// softmax over rows of 256 (S f32 -> att bf16), one wave per row
__global__ void softmax_k(const float* __restrict__ S, ushort* __restrict__ att) {
    int row = blockIdx.x * 4 + (threadIdx.x >> 6);
    int lane = threadIdx.x & 63;
    const float4 sv = *(const float4*)(S + (size_t)row * 256 + lane * 4);
    float m = fmaxf(fmaxf(sv.x, sv.y), fmaxf(sv.z, sv.w));
    for (int o = 32; o > 0; o >>= 1) m = fmaxf(m, __shfl_xor(m, o));
    float e0 = __expf(sv.x - m), e1 = __expf(sv.y - m);
    float e2 = __expf(sv.z - m), e3 = __expf(sv.w - m);
    float s = e0 + e1 + e2 + e3;
    for (int o = 32; o > 0; o >>= 1) s += __shfl_xor(s, o);
    float inv = 1.f / s;
    ushort4 o4;
    o4.x = f2bf(e0 * inv); o4.y = f2bf(e1 * inv);
    o4.z = f2bf(e2 * inv); o4.w = f2bf(e3 * inv);
    *(ushort4*)(att + (size_t)row * 256 + lane * 4) = o4;
}

// vbuf [p][j][512] -> vbufT [p][512][j] (64x64 LDS tiles)
__global__ void transpose_v_k(const ushort* __restrict__ vb, ushort* __restrict__ vt) {
    __shared__ ushort tl[64][66];
    int p = blockIdx.z, j0 = blockIdx.y * 64, c0 = blockIdx.x * 64;
    int t = threadIdx.x;
#pragma unroll
    for (int i = 0; i < 4; i++) {
        int e = i * 1024 + t * 4;
        int j = e >> 6, c = e & 63;
        ushort4 v = *(const ushort4*)(vb + ((size_t)p * 256 + j0 + j) * 512 + c0 + c);
        tl[j][c] = v.x; tl[j][c + 1] = v.y; tl[j][c + 2] = v.z; tl[j][c + 3] = v.w;
    }
    __syncthreads();
#pragma unroll
    for (int i = 0; i < 4; i++) {
        int e = i * 1024 + t * 4;
        int cc = e >> 6, jj = e & 63;
        ushort4 o;
        o.x = tl[jj][cc]; o.y = tl[jj + 1][cc]; o.z = tl[jj + 2][cc]; o.w = tl[jj + 3][cc];
        *(ushort4*)(vt + ((size_t)p * 512 + c0 + cc) * 256 + j0 + jj) = o;
    }
}

// layernorm over (c,p) per b + gamma/beta + relu; virt is bf16 [p][b][512]
__global__ __launch_bounds__(256) void ln_k(const ushort* __restrict__ virt, const float* __restrict__ gamma,
                                            const float* __restrict__ beta, ushort* __restrict__ vp) {
    int b = blockIdx.x, t = threadIdx.x;
    float s1 = 0.f, s2 = 0.f;
    for (int p = 0; p < 49; p++) {
        const ushort* r = virt + ((size_t)p * 256 + b) * 512;
        float a = bf2f(r[t]), c = bf2f(r[t + 256]);
        s1 += a + c;
        s2 += a * a + c * c;
    }
    for (int o = 32; o > 0; o >>= 1) { s1 += __shfl_xor(s1, o); s2 += __shfl_xor(s2, o); }
    __shared__ float red[8];
    int wave = t >> 6, lane = t & 63;
    if (lane == 0) { red[wave] = s1; red[4 + wave] = s2; }
    __syncthreads();
    float S1 = red[0] + red[1] + red[2] + red[3];
    float S2 = red[4] + red[5] + red[6] + red[7];
    float mean = S1 * (1.f / 25088.f);
    float var = S2 * (1.f / 25088.f) - mean * mean;
    float rs = rsqrtf(var + 1e-5f);
    float g0 = gamma[t], b0 = beta[t], g1 = gamma[t + 256], b1 = beta[t + 256];
    for (int p = 0; p < 49; p++) {
        const ushort* r = virt + ((size_t)p * 256 + b) * 512;
        size_t ob = ((size_t)(b * 9 + p / 7 + 1) * 9 + p % 7 + 1) * 512;
        vp[ob + t] = f2bf(fmaxf((bf2f(r[t]) - mean) * rs * g0 + b0, 0.f));
        vp[ob + t + 256] = f2bf(fmaxf((bf2f(r[t + 256]) - mean) * rs * g1 + b1, 0.f));
    }
#pragma unroll
    for (int e = 0; e < 32; e++) {  // zero padding borders
        int hp, wp;
        if (e < 9) { hp = 0; wp = e; }
        else if (e < 18) { hp = 8; wp = e - 9; }
        else { int e2 = e - 18; hp = 1 + (e2 >> 1); wp = (e2 & 1) ? 8 : 0; }
        size_t ob = ((size_t)(b * 9 + hp) * 9 + wp) * 512;
        vp[ob + t] = 0;
        vp[ob + t + 256] = 0;
    }
}

extern "C" void kernel_launch(void* const* d_in, const int* in_sizes, int n_in,
                              void* d_out, int out_size, void* d_ws, size_t ws_size,
                              hipStream_t stream) {
    const float* status = (const float*)d_in[0];
    const float* rois = (const float*)d_in[1];
    const float* bfeat = (const float*)d_in[2];
    const float* w_red = (const float*)d_in[3];
    const float* w_q = (const float*)d_in[4];
    const float* w_k = (const float*)d_in[5];
    const float* w_v = (const float*)d_in[6];
    const float* w_o = (const float*)d_in[7];
    const float* gamma = (const float*)d_in[8];
    const float* beta = (const float*)d_in[9];
    float* out = (float*)d_out;
    char* ws = (char*)d_ws;

    // ---- workspace layout (overlaid by lifetime), 182.5 MB peak ----
    // Region A [0, 51.4MB): bf16 partials P (4x12.8 or 2x25.7); later qb/S/att; then conv_out partials.
    const size_t OFF_P = 0;
    const size_t OFF_QB = 0;                         // 12,845,056 q [p][b][512]
    const size_t OFF_S = 12845056;                   // 12,845,056 S f32
    const size_t OFF_ATT = 25690112;                 //  6,422,528 att bf16
    // Region B [51.4MB, 146.9MB): x0T during conv_reduce; then:
    const size_t OFF_B = 51380224;
    const size_t OFF_XF = OFF_B;                     // 25,690,112 x f32 NCHW
    const size_t OFF_XPAD = OFF_B + 25690112;        // 21,233,664 xpad bf16 (later vpad)
    const size_t OFF_KB = OFF_B + 46923776;          // 12,845,056 kbuf [p][j][512]
    const size_t OFF_VB = OFF_B + 59768832;          // 12,845,056 vbuf (later virt bf16)
    const size_t OFF_VT = OFF_B + 72613888;          // 12,845,056 vbufT [p][512][j]
    // Region C: weights
    const size_t OFF_W1T = 146931712;                // 21,233,664
    const size_t OFF_WKVT = OFF_W1T + 21233664;      //  9,437,184
    const size_t OFF_WOT = OFF_WKVT + 9437184;       //  4,718,592
    const size_t OFF_WSQ = OFF_WOT + 4718592;        //    200,704
    const size_t NEED = OFF_WSQ + 200704;            // 182,521,856
    if (ws_size < NEED) return;

    // 1) prep: x0T borders + casts
    border_k<<<18432, 256, 0, stream>>>((ushort*)(ws + OFF_B), 2304, 256 * 32 * 576);
    cast_x0_k<<<dim3(4, 256), 256, 0, stream>>>(bfeat, (ushort*)(ws + OFF_B));
    cast_w_k<<<512, 256, 0, stream>>>(w_red, (ushort*)(ws + OFF_W1T), 2304);
    cast_w_k<<<512, 256, 0, stream>>>(w_k, (ushort*)(ws + OFF_WKVT), 512);
    cast_w_k<<<512, 256, 0, stream>>>(w_v, (ushort*)(ws + OFF_WKVT) + (size_t)512 * 9 * 512, 512);
    cast_w_k<<<512, 256, 0, stream>>>(w_o, (ushort*)(ws + OFF_WOT), 512);
    wsq_k<<<49, 512, 0, stream>>>(w_q, (float*)(ws + OFF_WSQ));
    // 2) conv_reduce split-K=4 -> bf16 partials, reduce -> XF + xpad
    gemm_bt<1, 0><<<dim3(4, 98, 4), 256, 0, stream>>>(
        (ushort*)(ws + OFF_B), (ushort*)(ws + OFF_W1T),
        nullptr, (ushort*)(ws + OFF_P),
        12544, 512, 20736, 2304, 9, 4);
    border_k<<<4096, 256, 0, stream>>>((ushort*)(ws + OFF_XPAD), 512, 256 * 32 * 128);
    reduce1_k<<<dim3(2, 256), 256, 0, stream>>>(
        (const ushort*)(ws + OFF_P), (float*)(ws + OFF_XF), (ushort*)(ws + OFF_XPAD));
    // 3) k & v convs fused, split-K=2 -> bf16 partials, reduce -> kbuf + vbuf
    gemm_bt<1, 0><<<dim3(8, 98, 2), 256, 0, stream>>>(
        (ushort*)(ws + OFF_XPAD), (ushort*)(ws + OFF_WKVT),
        nullptr, (ushort*)(ws + OFF_P),
        12544, 1024, 4608, 512, 9, 2);
    reduce_kv_k<<<6272, 256, 0, stream>>>(
        (const ushort*)(ws + OFF_P), (ushort*)(ws + OFF_KB), (ushort*)(ws + OFF_VB));
    transpose_v_k<<<dim3(8, 4, 49), 256, 0, stream>>>((ushort*)(ws + OFF_VB), (ushort*)(ws + OFF_VT));
    // 4) q path (qb overlays dead partials in region A)
    qgen_k<<<dim3(256, 49), 256, 0, stream>>>(status, rois, (float*)(ws + OFF_WSQ), (ushort*)(ws + OFF_QB));
    // 5) S = q.k^T per spatial position
    gemm_bt<0, 2><<<dim3(2, 2, 49), 256, 0, stream>>>(
        (ushort*)(ws + OFF_QB), (ushort*)(ws + OFF_KB),
        (float*)(ws + OFF_S), nullptr, 256, 256, 512, 512, 1, 1);
    // 6) softmax
    softmax_k<<<3136, 256, 0, stream>>>((float*)(ws + OFF_S), (ushort*)(ws + OFF_ATT));
    // 7) virt = att @ V (bf16 out, into dead vbuf slot)
    gemm_bt<0, 3><<<dim3(4, 2, 49), 256, 0, stream>>>(
        (ushort*)(ws + OFF_ATT), (ushort*)(ws + OFF_VT),
        nullptr, (ushort*)(ws + OFF_VB), 256, 512, 256, 256, 1, 1);
    // 8) layernorm + relu -> vpad (xpad slot)
    ln_k<<<256, 256, 0, stream>>>((const ushort*)(ws + OFF_VB), gamma, beta, (ushort*)(ws + OFF_XPAD));
    // 9) conv_out split-K=4 -> bf16 partials, then out = XF + sum(P)
    gemm_bt<1, 0><<<dim3(4, 98, 4), 256, 0, stream>>>(
        (ushort*)(ws + OFF_XPAD), (ushort*)(ws + OFF_WOT),
        nullptr, (ushort*)(ws + OFF_P),
        12544, 512, 4608, 512, 9, 4);
    reduce2_k<<<dim3(2, 256), 256, 0, stream>>>(
        (const ushort*)(ws + OFF_P), (const float*)(ws + OFF_XF), out);
}

// Round 6
// 924.662 us; speedup vs baseline: 1.7890x; 1.0761x over previous
//
#include <hip/hip_runtime.h>
#include <stdint.h>

#define AS1 __attribute__((address_space(1)))
#define AS3 __attribute__((address_space(3)))

typedef __bf16 bf16x8 __attribute__((ext_vector_type(8)));
typedef float  f32x4  __attribute__((ext_vector_type(4)));

__device__ __forceinline__ void gl_lds16(const void* g, void* l) {
    __builtin_amdgcn_global_load_lds((AS1 void*)g, (AS3 void*)l, 16, 0, 0);
}

// f32 -> bf16 round-to-nearest-even
__device__ __forceinline__ ushort f2bf(float f) {
    unsigned x = __float_as_uint(f);
    return (ushort)((x + 0x7fffu + ((x >> 16) & 1u)) >> 16);
}
__device__ __forceinline__ float bf2f(ushort u) {
    return __uint_as_float((unsigned)u << 16);
}

// ---------------------------------------------------------------------------
// GEMM: C[m][n] = sum_k A[m][k] * BT[n][k]
// 128x128 tile, BK=64 staged as 2 x 32-K chunks per barrier pair.
// AMODE 0: 3D grid; A flat [m][K]; blockIdx.z = batch
// AMODE 1: 1D grid (gridDim.x % 8 == 0), XCD-swizzled: L=(blockIdx.x),
//          W=(L&7)*(grid/8)+(L>>3); bx=W%NBX (n), by=(W/NBX)%98 (m),
//          bz=W/(NBX*98) (split-K chunk). Puts all NBX n-blocks of one
//          (m,z) group on one XCD => A-tile fetched once per XCD's L2.
//          conv gather: m=(b*49+p), k=(s*Cin+ci), ci in chunk bz.
// EPI 0: bf16 partials -> OU0[(z*M + m)*N + n]  (coalesced, reduced later)
// EPI 2: scores -> OF[z*256+m][n]  (256 wide, f32)
// EPI 3: PV     -> OU0[z*256+m][n] (512 wide, bf16)
// ---------------------------------------------------------------------------
template <int AMODE, int EPI, int NBX>
__global__ __launch_bounds__(256, 4) void gemm_bt(
    const ushort* __restrict__ A, const ushort* __restrict__ BT,
    float* __restrict__ OF, ushort* __restrict__ OU0,
    int M, int N, int K, int Cin, int Ksegs, int splitZ) {
    __shared__ ushort As[128 * 64];  // 2 chunks x (128 rows x 32 k)
    __shared__ ushort Bs[128 * 64];

    const int t = threadIdx.x;
    const int lane = t & 63;
    const int wave = t >> 6;
    const int wm = wave & 1, wn = wave >> 1;

    int bxi, byi, bzi;
    if (AMODE == 1) {
        unsigned L = blockIdx.x;
        unsigned S = gridDim.x >> 3;
        unsigned W = (L & 7u) * S + (L >> 3);
        bxi = (int)(W % (unsigned)NBX);
        unsigned rest = W / (unsigned)NBX;
        byi = (int)(rest % 98u);
        bzi = (int)(rest / 98u);
    } else {
        bxi = blockIdx.x; byi = blockIdx.y; bzi = blockIdx.z;
    }
    const int blockN = bxi * 128;
    const int blockM = byi * 128;
    const int z = bzi;

    const char* Ab = (const char*)A;
    const char* Bb = (const char*)BT;
    if (AMODE == 0) {
        Ab += (size_t)z * (size_t)M * (size_t)K * 2;
        Bb += (size_t)z * (size_t)N * (size_t)K * 2;
    }

    const int rS = t >> 2;              // staging row 0..63 (and +64)
    const int seg = (t & 3) * 16;       // 16B segment within a 64B K-tile row

    unsigned abase0, abase1;
    if (AMODE == 1) {
        int m0 = blockM + rS, m1 = m0 + 64;
        int b0 = m0 / 49, p0 = m0 % 49;
        int b1 = m1 / 49, p1 = m1 % 49;
        abase0 = (unsigned)(((b0 * 9 + p0 / 7) * 9 + p0 % 7) * Cin);
        abase1 = (unsigned)(((b1 * 9 + p1 / 7) * 9 + p1 % 7) * Cin);
    } else {
        abase0 = (unsigned)((blockM + rS) * K);
        abase1 = abase0 + (unsigned)(64 * K);
    }
    const unsigned bbase0 = (unsigned)((blockN + rS) * K);
    const unsigned bbase1 = bbase0 + (unsigned)(64 * K);

    f32x4 zero = {0.f, 0.f, 0.f, 0.f};
    f32x4 acc[4][4];
    for (int i = 0; i < 4; i++)
        for (int j = 0; j < 4; j++) acc[i][j] = zero;

    const unsigned chunk = (AMODE == 1) ? (unsigned)(Cin / splitZ) : (unsigned)K;
    const unsigned ciBase = (AMODE == 1) ? (unsigned)z * chunk : 0u;
    const int citers2 = (int)(chunk / 64);  // BK=64 iters
    const int nseg = (AMODE == 1) ? Ksegs : 1;

    for (int s = 0; s < nseg; ++s) {
        const char *aseg0, *aseg1, *bseg0, *bseg1;
        if (AMODE == 1) {
            unsigned shift = (unsigned)(((s / 3) * 9 + (s % 3)) * Cin) + ciBase;
            aseg0 = Ab + (size_t)(abase0 + shift) * 2 + seg;
            aseg1 = Ab + (size_t)(abase1 + shift) * 2 + seg;
            unsigned bshift = (unsigned)(s * Cin) + ciBase;
            bseg0 = Bb + (size_t)(bbase0 + bshift) * 2 + seg;
            bseg1 = Bb + (size_t)(bbase1 + bshift) * 2 + seg;
        } else {
            aseg0 = Ab + (size_t)abase0 * 2 + seg;
            aseg1 = Ab + (size_t)abase1 * 2 + seg;
            bseg0 = Bb + (size_t)bbase0 * 2 + seg;
            bseg1 = Bb + (size_t)bbase1 * 2 + seg;
        }

        for (int ct = 0; ct < citers2; ++ct) {
            const int o0 = ct * 128;       // chunk 0 (32 k = 64 B)
            const int o1 = ct * 128 + 64;  // chunk 1
            __syncthreads();  // previous compute done reading LDS
            gl_lds16(aseg0 + o0, (char*)As + t * 16);
            gl_lds16(aseg1 + o0, (char*)As + 4096 + t * 16);
            gl_lds16(bseg0 + o0, (char*)Bs + t * 16);
            gl_lds16(bseg1 + o0, (char*)Bs + 4096 + t * 16);
            gl_lds16(aseg0 + o1, (char*)As + 8192 + t * 16);
            gl_lds16(aseg1 + o1, (char*)As + 12288 + t * 16);
            gl_lds16(bseg0 + o1, (char*)Bs + 8192 + t * 16);
            gl_lds16(bseg1 + o1, (char*)Bs + 12288 + t * 16);
            __syncthreads();  // staging visible

#pragma unroll
            for (int h = 0; h < 2; ++h) {
                const ushort* Ap = As + h * 4096 + (wm * 64 + (lane & 15)) * 32 + (lane >> 4) * 8;
                const ushort* Bp = Bs + h * 4096 + (wn * 64 + (lane & 15)) * 32 + (lane >> 4) * 8;
                bf16x8 af[4], bfr[4];
#pragma unroll
                for (int i = 0; i < 4; i++) {
                    af[i] = *(const bf16x8*)(Ap + i * 16 * 32);
                    bfr[i] = *(const bf16x8*)(Bp + i * 16 * 32);
                }
#pragma unroll
                for (int i = 0; i < 4; i++)
#pragma unroll
                    for (int j = 0; j < 4; j++)
                        acc[i][j] = __builtin_amdgcn_mfma_f32_16x16x32_bf16(af[i], bfr[j], acc[i][j], 0, 0, 0);
            }
        }
    }

    // epilogue: C/D layout col=lane&15, row=(lane>>4)*4+r  [m89/m91 verified]
    const int mrow = (lane >> 4) * 4;
    const int ncol = lane & 15;
#pragma unroll
    for (int i = 0; i < 4; i++) {
#pragma unroll
        for (int j = 0; j < 4; j++) {
            f32x4 v = acc[i][j];
#pragma unroll
            for (int r = 0; r < 4; r++) {
                int m = blockM + wm * 64 + i * 16 + mrow + r;
                int n = blockN + wn * 64 + j * 16 + ncol;
                float val = v[r];
                if (EPI == 0) {
                    OU0[((size_t)z * M + m) * N + n] = f2bf(val);
                } else if (EPI == 2) {
                    OF[((size_t)z * 256 + m) * 256 + n] = val;
                } else {
                    OU0[((size_t)z * 256 + m) * 512 + n] = f2bf(val);
                }
            }
        }
    }
}

// zero only the 32 border cells of a padded [256][9][9][C] bf16 tensor
__global__ void border_k(ushort* __restrict__ base, int C, int nvec) {
    int id = blockIdx.x * 256 + threadIdx.x;
    if (id >= nvec) return;
    int cpc = C >> 2;
    int c4 = (id % cpc) * 4;
    int r = id / cpc;
    int cell = r & 31, b = r >> 5;
    int hp, wp;
    if (cell < 9) { hp = 0; wp = cell; }
    else if (cell < 18) { hp = 8; wp = cell - 9; }
    else { int e2 = cell - 18; hp = 1 + (e2 >> 1); wp = (e2 & 1) ? 8 : 0; }
    ushort4 zz = {0, 0, 0, 0};
    *(ushort4*)(base + ((size_t)(b * 9 + hp) * 9 + wp) * C + c4) = zz;
}

// reduce1: sum 4 bf16 partials [z][m=(b,p)][512] -> XF f32 [b][c][p] + xpad bf16
__global__ __launch_bounds__(256) void reduce1_k(const ushort* __restrict__ P,
                                                 float* __restrict__ XF, ushort* __restrict__ xp) {
    __shared__ float lf[256 * 49];  // [c][p]
    int h = blockIdx.x, b = blockIdx.y, t = threadIdx.x;
    const size_t zs = (size_t)12544 * 512;
    const ushort* base = P + ((size_t)b * 49) * 512 + h * 256;
    for (int e = t; e < 49 * 64; e += 256) {
        int p = e >> 6, c4 = (e & 63) << 2;
        float s0 = 0.f, s1 = 0.f, s2 = 0.f, s3 = 0.f;
#pragma unroll
        for (int z = 0; z < 4; z++) {
            ushort4 u = *(const ushort4*)(base + zs * z + (size_t)p * 512 + c4);
            s0 += bf2f(u.x); s1 += bf2f(u.y); s2 += bf2f(u.z); s3 += bf2f(u.w);
        }
        ushort4 o;
        o.x = f2bf(s0); o.y = f2bf(s1); o.z = f2bf(s2); o.w = f2bf(s3);
        *(ushort4*)(xp + (size_t)((b * 9 + p / 7 + 1) * 9 + p % 7 + 1) * 512 + h * 256 + c4) = o;
        lf[(c4 + 0) * 49 + p] = s0;
        lf[(c4 + 1) * 49 + p] = s1;
        lf[(c4 + 2) * 49 + p] = s2;
        lf[(c4 + 3) * 49 + p] = s3;
    }
    __syncthreads();
    float* xfb = XF + (size_t)b * 25088 + h * 12544;
    for (int e = t; e < 256 * 49; e += 256) xfb[e] = lf[e];
}

// reduce2: out NCHW = XF + sum of 4 bf16 partials (transposed)
__global__ __launch_bounds__(256) void reduce2_k(const ushort* __restrict__ P,
                                                 const float* __restrict__ XF, float* __restrict__ out) {
    __shared__ float lf[256 * 49];
    int h = blockIdx.x, b = blockIdx.y, t = threadIdx.x;
    const size_t zs = (size_t)12544 * 512;
    const ushort* base = P + ((size_t)b * 49) * 512 + h * 256;
    for (int e = t; e < 49 * 64; e += 256) {
        int p = e >> 6, c4 = (e & 63) << 2;
        float s0 = 0.f, s1 = 0.f, s2 = 0.f, s3 = 0.f;
#pragma unroll
        for (int z = 0; z < 4; z++) {
            ushort4 u = *(const ushort4*)(base + zs * z + (size_t)p * 512 + c4);
            s0 += bf2f(u.x); s1 += bf2f(u.y); s2 += bf2f(u.z); s3 += bf2f(u.w);
        }
        lf[(c4 + 0) * 49 + p] = s0;
        lf[(c4 + 1) * 49 + p] = s1;
        lf[(c4 + 2) * 49 + p] = s2;
        lf[(c4 + 3) * 49 + p] = s3;
    }
    __syncthreads();
    const float* xfb = XF + (size_t)b * 25088 + h * 12544;
    float* ob = out + (size_t)b * 25088 + h * 12544;
    for (int e = t; e < 256 * 49; e += 256) ob[e] = xfb[e] + lf[e];
}

// reduce_kv: sum 2 bf16 partials [z][m][1024] -> kbuf [p][j][512] + vbuf [p][j][512]
__global__ void reduce_kv_k(const ushort* __restrict__ P,
                            ushort* __restrict__ kb, ushort* __restrict__ vb) {
    int id = blockIdx.x * 256 + threadIdx.x;  // 12544 * 128 items
    int n8 = id & 127, m = id >> 7;
    int b = m / 49, p = m % 49;
    const ushort* p0 = P + (size_t)m * 1024 + n8 * 8;
    const ushort* p1 = p0 + (size_t)12544 * 1024;
    ushort4 a0 = *(const ushort4*)p0, a1 = *(const ushort4*)(p0 + 4);
    ushort4 b0 = *(const ushort4*)p1, b1 = *(const ushort4*)(p1 + 4);
    ushort4 o0, o1;
    o0.x = f2bf(bf2f(a0.x) + bf2f(b0.x)); o0.y = f2bf(bf2f(a0.y) + bf2f(b0.y));
    o0.z = f2bf(bf2f(a0.z) + bf2f(b0.z)); o0.w = f2bf(bf2f(a0.w) + bf2f(b0.w));
    o1.x = f2bf(bf2f(a1.x) + bf2f(b1.x)); o1.y = f2bf(bf2f(a1.y) + bf2f(b1.y));
    o1.z = f2bf(bf2f(a1.z) + bf2f(b1.z)); o1.w = f2bf(bf2f(a1.w) + bf2f(b1.w));
    size_t dst = ((size_t)p * 256 + b) * 512;
    ushort* o = (n8 < 64) ? (kb + dst + n8 * 8) : (vb + dst + (n8 - 64) * 8);
    *(ushort4*)o = o0;
    *(ushort4*)(o + 4) = o1;
}

// bbox_featx f32 [b][2304][49] -> x0T bf16 [b][9][9][2304] interior
__global__ __launch_bounds__(256) void cast_x0_k(const float* __restrict__ in, ushort* __restrict__ out) {
    __shared__ ushort tl[576 * 49];  // [ci][p] within tile
    int cit = blockIdx.x, b = blockIdx.y, t = threadIdx.x;
    const float* src = in + ((size_t)b * 2304 + cit * 576) * 49;
    for (int e4 = t; e4 < 7056; e4 += 256) {
        float4 v = *(const float4*)(src + e4 * 4);
        ushort4 u;
        u.x = f2bf(v.x); u.y = f2bf(v.y); u.z = f2bf(v.z); u.w = f2bf(v.w);
        *(ushort4*)(tl + e4 * 4) = u;
    }
    __syncthreads();
    for (int e4 = t; e4 < 7056; e4 += 256) {  // 49 p * 144 c4-groups
        int p = e4 / 144, c4 = (e4 % 144) * 4;
        ushort4 u;
        u.x = tl[c4 * 49 + p]; u.y = tl[(c4 + 1) * 49 + p];
        u.z = tl[(c4 + 2) * 49 + p]; u.w = tl[(c4 + 3) * 49 + p];
        *(ushort4*)(out + (size_t)((b * 9 + p / 7 + 1) * 9 + p % 7 + 1) * 2304 + cit * 576 + c4) = u;
    }
}

// weight f32 [co][Cin][9] -> bf16 [co][9][Cin]  (one block per co)
__global__ void cast_w_k(const float* __restrict__ in, ushort* __restrict__ out, int Cin) {
    __shared__ float lds[256 * 9];
    int co = blockIdx.x, t = threadIdx.x;
    for (int ci0 = 0; ci0 < Cin; ci0 += 256) {
        const float* src = in + ((size_t)co * Cin + ci0 + t) * 9;
#pragma unroll
        for (int j = 0; j < 9; j++) lds[t * 9 + j] = src[j];
        __syncthreads();
#pragma unroll
        for (int s = 0; s < 9; s++) out[((size_t)co * 9 + s) * Cin + ci0 + t] = f2bf(lds[t * 9 + s]);
        __syncthreads();
    }
}

// windowed sums of w_q per spatial pos: WSQ[p][ci][co]
__global__ void wsq_k(const float* __restrict__ wq, float* __restrict__ WSQ) {
    int p = blockIdx.x, co = threadIdx.x;
    int h = p / 7, w = p % 7;
#pragma unroll
    for (int ci = 0; ci < 2; ci++) {
        float a = 0.f;
        for (int kh = 0; kh < 3; kh++) {
            int hi = h + kh - 1;
            if (hi < 0 || hi > 6) continue;
            for (int kw = 0; kw < 3; kw++) {
                int wi = w + kw - 1;
                if (wi < 0 || wi > 6) continue;
                a += wq[(((size_t)co * 2 + ci) * 3 + kh) * 3 + kw];
            }
        }
        WSQ[((size_t)p * 2 + ci) * 512 + co] = a;
    }
}

// q bf16 [p][b][512], scaled by 1/sqrt(512)
__global__ void qgen_k(const float* __restrict__ status, const float* __restrict__ rois,
                       const float* __restrict__ WSQ, ushort* __restrict__ qb) {
    int b = blockIdx.x, p = blockIdx.y, t = threadIdx.x;
    float st0 = status[b * 2], st1 = rois[b * 2 + 1];
    int c = t * 2;
    const float* w0 = WSQ + (size_t)p * 2 * 512;
    const float sc = 0.04419417382415922f;  // 1/sqrt(512)
    float q0 = (st0 * w0[c] + st1 * w0[512 + c]) * sc;
    float q1 = (st0 * w0[c + 1] + st1 * w0[512 + c + 1]) * sc;
    unsigned u = (unsigned)f2bf(q0) | ((unsigned)f2bf(q1) << 16);
    *(unsigned*)(qb + ((size_t)p * 256 + b) * 512 + c) = u;
}

// softmax over rows of 256 (S f32 -> att bf16), one wave per row
__global__ void softmax_k(const float* __restrict__ S, ushort* __restrict__ att) {
    int row = blockIdx.x * 4 + (threadIdx.x >> 6);
    int lane = threadIdx.x & 63;
    const float4 sv = *(const float4*)(S + (size_t)row * 256 + lane * 4);
    float m = fmaxf(fmaxf(sv.x, sv.y), fmaxf(sv.z, sv.w));
    for (int o = 32; o > 0; o >>= 1) m = fmaxf(m, __shfl_xor(m, o));
    float e0 = __expf(sv.x - m), e1 = __expf(sv.y - m);
    float e2 = __expf(sv.z - m), e3 = __expf(sv.w - m);
    float s = e0 + e1 + e2 + e3;
    for (int o = 32; o > 0; o >>= 1) s += __shfl_xor(s, o);
    float inv = 1.f / s;
    ushort4 o4;
    o4.x = f2bf(e0 * inv); o4.y = f2bf(e1 * inv);
    o4.z = f2bf(e2 * inv); o4.w = f2bf(e3 * inv);
    *(ushort4*)(att + (size_t)row * 256 + lane * 4) = o4;
}

// vbuf [p][j][512] -> vbufT [p][512][j] (64x64 LDS tiles)
__global__ void transpose_v_k(const ushort* __restrict__ vb, ushort* __restrict__ vt) {
    __shared__ ushort tl[64][66];
    int p = blockIdx.z, j0 = blockIdx.y * 64, c0 = blockIdx.x * 64;
    int t = threadIdx.x;
#pragma unroll
    for (int i = 0; i < 4; i++) {
        int e = i * 1024 + t * 4;
        int j = e >> 6, c = e & 63;
        ushort4 v = *(const ushort4*)(vb + ((size_t)p * 256 + j0 + j) * 512 + c0 + c);
        tl[j][c] = v.x; tl[j][c + 1] = v.y; tl[j][c + 2] = v.z; tl[j][c + 3] = v.w;
    }
    __syncthreads();
#pragma unroll
    for (int i = 0; i < 4; i++) {
        int e = i * 1024 + t * 4;
        int cc = e >> 6, jj = e & 63;
        ushort4 o;
        o.x = tl[jj][cc]; o.y = tl[jj + 1][cc]; o.z = tl[jj + 2][cc]; o.w = tl[jj + 3][cc];
        *(ushort4*)(vt + ((size_t)p * 512 + c0 + cc) * 256 + j0 + jj) = o;
    }
}

// layernorm over (c,p) per b + gamma/beta + relu; virt is bf16 [p][b][512]
__global__ __launch_bounds__(256) void ln_k(const ushort* __restrict__ virt, const float* __restrict__ gamma,
                                            const float* __restrict__ beta, ushort* __restrict__ vp) {
    int b = blockIdx.x, t = threadIdx.x;
    float s1 = 0.f, s2 = 0.f;
    for (int p = 0; p < 49; p++) {
        const ushort* r = virt + ((size_t)p * 256 + b) * 512;
        float a = bf2f(r[t]), c = bf2f(r[t + 256]);
        s1 += a + c;
        s2 += a * a + c * c;
    }
    for (int o = 32; o > 0; o >>= 1) { s1 += __shfl_xor(s1, o); s2 += __shfl_xor(s2, o); }
    __shared__ float red[8];
    int wave = t >> 6, lane = t & 63;
    if (lane == 0) { red[wave] = s1; red[4 + wave] = s2; }
    __syncthreads();
    float S1 = red[0] + red[1] + red[2] + red[3];
    float S2 = red[4] + red[5] + red[6] + red[7];
    float mean = S1 * (1.f / 25088.f);
    float var = S2 * (1.f / 25088.f) - mean * mean;
    float rs = rsqrtf(var + 1e-5f);
    float g0 = gamma[t], b0 = beta[t], g1 = gamma[t + 256], b1 = beta[t + 256];
    for (int p = 0; p < 49; p++) {
        const ushort* r = virt + ((size_t)p * 256 + b) * 512;
        size_t ob = ((size_t)(b * 9 + p / 7 + 1) * 9 + p % 7 + 1) * 512;
        vp[ob + t] = f2bf(fmaxf((bf2f(r[t]) - mean) * rs * g0 + b0, 0.f));
        vp[ob + t + 256] = f2bf(fmaxf((bf2f(r[t + 256]) - mean) * rs * g1 + b1, 0.f));
    }
#pragma unroll
    for (int e = 0; e < 32; e++) {  // zero padding borders
        int hp, wp;
        if (e < 9) { hp = 0; wp = e; }
        else if (e < 18) { hp = 8; wp = e - 9; }
        else { int e2 = e - 18; hp = 1 + (e2 >> 1); wp = (e2 & 1) ? 8 : 0; }
        size_t ob = ((size_t)(b * 9 + hp) * 9 + wp) * 512;
        vp[ob + t] = 0;
        vp[ob + t + 256] = 0;
    }
}

extern "C" void kernel_launch(void* const* d_in, const int* in_sizes, int n_in,
                              void* d_out, int out_size, void* d_ws, size_t ws_size,
                              hipStream_t stream) {
    const float* status = (const float*)d_in[0];
    const float* rois = (const float*)d_in[1];
    const float* bfeat = (const float*)d_in[2];
    const float* w_red = (const float*)d_in[3];
    const float* w_q = (const float*)d_in[4];
    const float* w_k = (const float*)d_in[5];
    const float* w_v = (const float*)d_in[6];
    const float* w_o = (const float*)d_in[7];
    const float* gamma = (const float*)d_in[8];
    const float* beta = (const float*)d_in[9];
    float* out = (float*)d_out;
    char* ws = (char*)d_ws;

    // ---- workspace layout (overlaid by lifetime), 182.5 MB peak ----
    // Region A [0, 51.4MB): bf16 partials P; later qb/S/att; then conv_out partials.
    const size_t OFF_P = 0;
    const size_t OFF_QB = 0;                         // 12,845,056 q [p][b][512]
    const size_t OFF_S = 12845056;                   // 12,845,056 S f32
    const size_t OFF_ATT = 25690112;                 //  6,422,528 att bf16
    // Region B [51.4MB, 146.9MB): x0T during conv_reduce; then:
    const size_t OFF_B = 51380224;
    const size_t OFF_XF = OFF_B;                     // 25,690,112 x f32 NCHW
    const size_t OFF_XPAD = OFF_B + 25690112;        // 21,233,664 xpad bf16 (later vpad)
    const size_t OFF_KB = OFF_B + 46923776;          // 12,845,056 kbuf [p][j][512]
    const size_t OFF_VB = OFF_B + 59768832;          // 12,845,056 vbuf (later virt bf16)
    const size_t OFF_VT = OFF_B + 72613888;          // 12,845,056 vbufT [p][512][j]
    // Region C: weights
    const size_t OFF_W1T = 146931712;                // 21,233,664
    const size_t OFF_WKVT = OFF_W1T + 21233664;      //  9,437,184
    const size_t OFF_WOT = OFF_WKVT + 9437184;       //  4,718,592
    const size_t OFF_WSQ = OFF_WOT + 4718592;        //    200,704
    const size_t NEED = OFF_WSQ + 200704;            // 182,521,856
    if (ws_size < NEED) return;

    // 1) prep: x0T borders + casts
    border_k<<<18432, 256, 0, stream>>>((ushort*)(ws + OFF_B), 2304, 256 * 32 * 576);
    cast_x0_k<<<dim3(4, 256), 256, 0, stream>>>(bfeat, (ushort*)(ws + OFF_B));
    cast_w_k<<<512, 256, 0, stream>>>(w_red, (ushort*)(ws + OFF_W1T), 2304);
    cast_w_k<<<512, 256, 0, stream>>>(w_k, (ushort*)(ws + OFF_WKVT), 512);
    cast_w_k<<<512, 256, 0, stream>>>(w_v, (ushort*)(ws + OFF_WKVT) + (size_t)512 * 9 * 512, 512);
    cast_w_k<<<512, 256, 0, stream>>>(w_o, (ushort*)(ws + OFF_WOT), 512);
    wsq_k<<<49, 512, 0, stream>>>(w_q, (float*)(ws + OFF_WSQ));
    // 2) conv_reduce split-K=4, XCD-swizzled 1D grid (4n x 98m x 4z = 1568)
    gemm_bt<1, 0, 4><<<1568, 256, 0, stream>>>(
        (ushort*)(ws + OFF_B), (ushort*)(ws + OFF_W1T),
        nullptr, (ushort*)(ws + OFF_P),
        12544, 512, 20736, 2304, 9, 4);
    border_k<<<4096, 256, 0, stream>>>((ushort*)(ws + OFF_XPAD), 512, 256 * 32 * 128);
    reduce1_k<<<dim3(2, 256), 256, 0, stream>>>(
        (const ushort*)(ws + OFF_P), (float*)(ws + OFF_XF), (ushort*)(ws + OFF_XPAD));
    // 3) k & v convs fused, split-K=2, swizzled (8n x 98m x 2z = 1568)
    gemm_bt<1, 0, 8><<<1568, 256, 0, stream>>>(
        (ushort*)(ws + OFF_XPAD), (ushort*)(ws + OFF_WKVT),
        nullptr, (ushort*)(ws + OFF_P),
        12544, 1024, 4608, 512, 9, 2);
    reduce_kv_k<<<6272, 256, 0, stream>>>(
        (const ushort*)(ws + OFF_P), (ushort*)(ws + OFF_KB), (ushort*)(ws + OFF_VB));
    transpose_v_k<<<dim3(8, 4, 49), 256, 0, stream>>>((ushort*)(ws + OFF_VB), (ushort*)(ws + OFF_VT));
    // 4) q path (qb overlays dead partials in region A)
    qgen_k<<<dim3(256, 49), 256, 0, stream>>>(status, rois, (float*)(ws + OFF_WSQ), (ushort*)(ws + OFF_QB));
    // 5) S = q.k^T per spatial position
    gemm_bt<0, 2, 1><<<dim3(2, 2, 49), 256, 0, stream>>>(
        (ushort*)(ws + OFF_QB), (ushort*)(ws + OFF_KB),
        (float*)(ws + OFF_S), nullptr, 256, 256, 512, 512, 1, 1);
    // 6) softmax
    softmax_k<<<3136, 256, 0, stream>>>((float*)(ws + OFF_S), (ushort*)(ws + OFF_ATT));
    // 7) virt = att @ V (bf16 out, into dead vbuf slot)
    gemm_bt<0, 3, 1><<<dim3(4, 2, 49), 256, 0, stream>>>(
        (ushort*)(ws + OFF_ATT), (ushort*)(ws + OFF_VT),
        nullptr, (ushort*)(ws + OFF_VB), 256, 512, 256, 256, 1, 1);
    // 8) layernorm + relu -> vpad (xpad slot)
    ln_k<<<256, 256, 0, stream>>>((const ushort*)(ws + OFF_VB), gamma, beta, (ushort*)(ws + OFF_XPAD));
    // 9) conv_out split-K=4, swizzled (4n x 98m x 4z = 1568), then out = XF + sum(P)
    gemm_bt<1, 0, 4><<<1568, 256, 0, stream>>>(
        (ushort*)(ws + OFF_XPAD), (ushort*)(ws + OFF_WOT),
        nullptr, (ushort*)(ws + OFF_P),
        12544, 512, 4608, 512, 9, 4);
    reduce2_k<<<dim3(2, 256), 256, 0, stream>>>(
        (const ushort*)(ws + OFF_P), (const float*)(ws + OFF_XF), out);
}